// Round 14
// baseline (1697.835 us; speedup 1.0000x reference)
//
#include <hip/hip_runtime.h>
#include <hip/hip_bf16.h>

#define SEQ 2048
#define BATCH 2
#define NH 16
#define DM 1024
#define DEPTH 64
#define MROWS (BATCH * SEQ)   // 4096

typedef __attribute__((ext_vector_type(8))) short bf16x8;
typedef __attribute__((ext_vector_type(4))) float f32x4;

__device__ __forceinline__ float b2f(ushort u) {
    union { uint i; float f; } v; v.i = ((uint)u) << 16; return v.f;
}
__device__ __forceinline__ ushort f2b(float f) {
    __hip_bfloat16 h = __float2bfloat16(f);
    return *reinterpret_cast<ushort*>(&h);
}

__device__ __forceinline__ void gload_lds16(const void* g, void* l) {
    __builtin_amdgcn_global_load_lds((const __attribute__((address_space(1))) void*)g,
                                     (__attribute__((address_space(3))) void*)l, 16, 0, 0);
}

// ---------------- fp32 -> bf16 elementwise ----------------
__global__ __launch_bounds__(256) void convert_f32_bf16(const float* __restrict__ in,
                                                        ushort* __restrict__ outp, int n4) {
    int i = blockIdx.x * 256 + threadIdx.x;
    if (i < n4) {
        const float4 v = ((const float4*)in)[i];
        ushort4 o;
        o.x = f2b(v.x); o.y = f2b(v.y); o.z = f2b(v.z); o.w = f2b(v.w);
        ((ushort4*)outp)[i] = o;
    }
}

// ---------------- 4x fused: fp32 W[K][N] -> bf16 Wt[N][K], z selects weight ----------------
__global__ __launch_bounds__(256) void transpose_convert4(const float* __restrict__ w0,
                                                          const float* __restrict__ w1,
                                                          const float* __restrict__ w2,
                                                          const float* __restrict__ w3,
                                                          ushort* __restrict__ WtBase) {
    __shared__ float tile[32][33];
    const int z = blockIdx.z;
    const float* W = (z == 0) ? w0 : (z == 1) ? w1 : (z == 2) ? w2 : w3;
    ushort* Wt = WtBase + (size_t)z * DM * DM;
    const int bx = blockIdx.x * 32;  // n base
    const int by = blockIdx.y * 32;  // k base
    const int tx = threadIdx.x & 31, ty = threadIdx.x >> 5;
#pragma unroll
    for (int i = 0; i < 32; i += 8)
        tile[ty + i][tx] = W[(size_t)(by + ty + i) * DM + bx + tx];
    __syncthreads();
#pragma unroll
    for (int i = 0; i < 32; i += 8)
        Wt[(size_t)(bx + ty + i) * DM + by + tx] = f2b(tile[tx][ty + i]);
}

// ---------------- fused QKV GEMM: [4096,1024] @ [1024,3072] + bias -> bf16 ----------------
// Q bank (bank==0) is pre-scaled by 1/sqrt(DEPTH)=0.125 so attn skips the logit scale.
__global__ __launch_bounds__(256) void gemm_qkv_mfma(const ushort* __restrict__ A,
                                                     const ushort* __restrict__ WtAll,
                                                     const float* __restrict__ bq,
                                                     const float* __restrict__ bk,
                                                     const float* __restrict__ bv,
                                                     ushort* __restrict__ OutBase) {
    __shared__ __align__(16) ushort As[128 * 32];
    __shared__ __align__(16) ushort Bs[128 * 32];

    const int t    = threadIdx.x;
    const int lane = t & 63;
    const int w    = t >> 6;
    const int wr   = w >> 1, wc = w & 1;
    const int row0 = blockIdx.y * 128;
    const int col0 = blockIdx.x * 128;           // 0..2944
    const int bank = col0 >> 10;                 // 0,1,2
    const float* bias = (bank == 0) ? bq : (bank == 1) ? bk : bv;
    const float scale = (bank == 0) ? 0.125f : 1.0f;
    const int ccol0 = col0 & 1023;
    ushort* Cout = OutBase + (size_t)bank * MROWS * DM;

    f32x4 acc[4][4];
#pragma unroll
    for (int mi = 0; mi < 4; ++mi)
#pragma unroll
        for (int ni = 0; ni < 4; ++ni) acc[mi][ni] = (f32x4){0.f, 0.f, 0.f, 0.f};

    const int sr = t >> 2;
    const int sc = (t & 3) * 8;

    for (int k0 = 0; k0 < DM; k0 += 32) {
        gload_lds16(&A[(size_t)(row0 + sr) * DM + k0 + sc],          &As[w * 512]);
        gload_lds16(&A[(size_t)(row0 + 64 + sr) * DM + k0 + sc],     &As[2048 + w * 512]);
        gload_lds16(&WtAll[(size_t)(col0 + sr) * DM + k0 + sc],      &Bs[w * 512]);
        gload_lds16(&WtAll[(size_t)(col0 + 64 + sr) * DM + k0 + sc], &Bs[2048 + w * 512]);
        __syncthreads();

        bf16x8 af[4], bfr[4];
#pragma unroll
        for (int mi = 0; mi < 4; ++mi)
            af[mi] = *(const bf16x8*)&As[(wr * 64 + mi * 16 + (lane & 15)) * 32 + (lane >> 4) * 8];
#pragma unroll
        for (int ni = 0; ni < 4; ++ni)
            bfr[ni] = *(const bf16x8*)&Bs[(wc * 64 + ni * 16 + (lane & 15)) * 32 + (lane >> 4) * 8];
#pragma unroll
        for (int mi = 0; mi < 4; ++mi)
#pragma unroll
            for (int ni = 0; ni < 4; ++ni)
                acc[mi][ni] = __builtin_amdgcn_mfma_f32_16x16x32_bf16(af[mi], bfr[ni], acc[mi][ni], 0, 0, 0);
        __syncthreads();
    }

    float bb[4];
#pragma unroll
    for (int ni = 0; ni < 4; ++ni) bb[ni] = bias[ccol0 + wc * 64 + ni * 16 + (lane & 15)];

#pragma unroll
    for (int mi = 0; mi < 4; ++mi) {
        const int row = row0 + wr * 64 + mi * 16 + (lane >> 4) * 4;
#pragma unroll
        for (int ni = 0; ni < 4; ++ni) {
            const int col = ccol0 + wc * 64 + ni * 16 + (lane & 15);
#pragma unroll
            for (int r = 0; r < 4; ++r)
                Cout[(size_t)(row + r) * DM + col] = f2b((acc[mi][ni][r] + bb[ni]) * scale);
        }
    }
}

// ---------------- bf16 MFMA GEMM: C = A @ Wt^T + bias, fp32 out ----------------
__global__ __launch_bounds__(256) void gemm_mfma_f32(const ushort* __restrict__ A,
                                                     const ushort* __restrict__ Wt,
                                                     const float* __restrict__ bias,
                                                     float* __restrict__ Cout) {
    __shared__ __align__(16) ushort As[128 * 32];
    __shared__ __align__(16) ushort Bs[128 * 32];

    const int t    = threadIdx.x;
    const int lane = t & 63;
    const int w    = t >> 6;
    const int wr   = w >> 1, wc = w & 1;
    const int row0 = blockIdx.y * 128;
    const int col0 = blockIdx.x * 128;

    f32x4 acc[4][4];
#pragma unroll
    for (int mi = 0; mi < 4; ++mi)
#pragma unroll
        for (int ni = 0; ni < 4; ++ni) acc[mi][ni] = (f32x4){0.f, 0.f, 0.f, 0.f};

    const int sr = t >> 2;
    const int sc = (t & 3) * 8;

    for (int k0 = 0; k0 < DM; k0 += 32) {
        gload_lds16(&A[(size_t)(row0 + sr) * DM + k0 + sc],       &As[w * 512]);
        gload_lds16(&A[(size_t)(row0 + 64 + sr) * DM + k0 + sc],  &As[2048 + w * 512]);
        gload_lds16(&Wt[(size_t)(col0 + sr) * DM + k0 + sc],      &Bs[w * 512]);
        gload_lds16(&Wt[(size_t)(col0 + 64 + sr) * DM + k0 + sc], &Bs[2048 + w * 512]);
        __syncthreads();

        bf16x8 af[4], bfr[4];
#pragma unroll
        for (int mi = 0; mi < 4; ++mi)
            af[mi] = *(const bf16x8*)&As[(wr * 64 + mi * 16 + (lane & 15)) * 32 + (lane >> 4) * 8];
#pragma unroll
        for (int ni = 0; ni < 4; ++ni)
            bfr[ni] = *(const bf16x8*)&Bs[(wc * 64 + ni * 16 + (lane & 15)) * 32 + (lane >> 4) * 8];
#pragma unroll
        for (int mi = 0; mi < 4; ++mi)
#pragma unroll
            for (int ni = 0; ni < 4; ++ni)
                acc[mi][ni] = __builtin_amdgcn_mfma_f32_16x16x32_bf16(af[mi], bfr[ni], acc[mi][ni], 0, 0, 0);
        __syncthreads();
    }

    float bb[4];
#pragma unroll
    for (int ni = 0; ni < 4; ++ni) bb[ni] = bias[col0 + wc * 64 + ni * 16 + (lane & 15)];

#pragma unroll
    for (int mi = 0; mi < 4; ++mi) {
        const int row = row0 + wr * 64 + mi * 16 + (lane >> 4) * 4;
#pragma unroll
        for (int ni = 0; ni < 4; ++ni) {
            const int col = col0 + wc * 64 + ni * 16 + (lane & 15);
#pragma unroll
            for (int r = 0; r < 4; ++r)
                Cout[(size_t)(row + r) * DM + col] = acc[mi][ni][r] + bb[ni];
        }
    }
}

// ---------------- V panel transpose: Vh[B,S,H*64] -> Vt[32][64 d][2048 k] bf16 ----------------
__global__ __launch_bounds__(256) void transpose_v(const ushort* __restrict__ Vh,
                                                   ushort* __restrict__ Vt) {
    __shared__ ushort tile[64][80];
    const int t  = threadIdx.x;
    const int bh = blockIdx.x;
    const int k0 = blockIdx.y * 64;
    const int b  = bh >> 4;
    const int h  = bh & 15;
    const size_t panel = (size_t)b * SEQ * DM + (size_t)h * DEPTH;

    {
        const int k = t >> 2, dc = (t & 3) * 16;
        const ushort* src = Vh + panel + (size_t)(k0 + k) * DM + dc;
        *(bf16x8*)&tile[k][dc]     = *(const bf16x8*)src;
        *(bf16x8*)&tile[k][dc + 8] = *(const bf16x8*)(src + 8);
    }
    __syncthreads();
    {
        const int d = t >> 2, kc = (t & 3) * 16;
        bf16x8 o0, o1;
#pragma unroll
        for (int j = 0; j < 8; ++j) o0[j] = tile[kc + j][d];
#pragma unroll
        for (int j = 0; j < 8; ++j) o1[j] = tile[kc + 8 + j][d];
        ushort* dst = Vt + ((size_t)bh * DEPTH + d) * SEQ + k0 + kc;
        *(bf16x8*)dst       = o0;
        *(bf16x8*)(dst + 8) = o1;
    }
}

// ---------------- fused attention v7: K-staged QK + pipelined PV; phase-ablation modes --------
// MODE 0: full (real). MODE 1: no attn store. MODE 2: no PV. MODE 3: QK+softmax only.
// Dummies at 4x grid (blockIdx.y & 31) surface above harness fill kernels with counters.
template <int MODE>
__global__ __launch_bounds__(512, 2) void attn_fused_kernel(const ushort* __restrict__ Qh,
                                                            const ushort* __restrict__ Kh,
                                                            const ushort* __restrict__ Vt,
                                                            float* __restrict__ attn_out,
                                                            ushort* __restrict__ Ctx) {
    __shared__ __align__(16) ushort P_lds[16 * 2048];   // 64 KB: K staging, then P tile
    __shared__ float red[256];                          // softmax stats

    const int t    = threadIdx.x;
    const int lane = t & 63;
    const int w    = t >> 6;          // 0..7
    const int qt   = blockIdx.x;      // fast axis -> panel-major dispatch
    const int bh   = blockIdx.y & 31;
    const int b    = bh >> 4;
    const int h    = bh & 15;
    const int q0   = qt * 16;
    const int q    = lane & 15;
    const int g    = lane >> 4;       // 0..3
    const int swzP = (q & 7) << 4;
    const int swzK = (q & 7) << 4;

    const size_t panel = (size_t)b * SEQ * DM + (size_t)h * DEPTH;
    char* Pb = (char*)P_lds;

    const ushort* Qrow = Qh + panel + (size_t)(q0 + q) * DM + g * 8;
    const bf16x8 qf0 = *(const bf16x8*)Qrow;
    const bf16x8 qf1 = *(const bf16x8*)(Qrow + 32);

    f32x4 acc[16];
#pragma unroll
    for (int i = 0; i < 16; ++i) acc[i] = (f32x4){0.f, 0.f, 0.f, 0.f};

    // ---- K staging (verified R13): chunk c -> buffer c&1; swizzle on GLOBAL source col.
    const char* Ksrc = (const char*)(Kh + panel);
    const int srow  = t >> 3;
    const int scolb = ((t & 7) * 16) ^ ((srow & 7) << 4);
    char* wavedst = Pb + (t >> 6) * 1024;

#define STAGE_K(c)                                                                  \
    {                                                                               \
        char* dB = wavedst + ((c) & 1) * 32768;                                     \
        _Pragma("unroll")                                                           \
        for (int j = 0; j < 4; ++j) {                                               \
            const char* gp = Ksrc + (size_t)((c) * 256 + j * 64 + srow) * (DM * 2)  \
                             + scolb;                                               \
            gload_lds16(gp, dB + j * 8192);                                         \
        }                                                                           \
    }

    STAGE_K(0);
    __syncthreads();

#pragma unroll
    for (int c = 0; c < 8; ++c) {
        if (c < 7) STAGE_K(c + 1);
        const char* kb = Pb + (c & 1) * 32768;
#pragma unroll
        for (int kt2 = 0; kt2 < 2; ++kt2) {
            const char* rowp = kb + (w * 32 + kt2 * 16 + q) * 128;
            const bf16x8 kf0 = *(const bf16x8*)(rowp + ((g * 16) ^ swzK));
            const bf16x8 kf1 = *(const bf16x8*)(rowp + ((64 + g * 16) ^ swzK));
            acc[c * 2 + kt2] = __builtin_amdgcn_mfma_f32_16x16x32_bf16(kf0, qf0, acc[c * 2 + kt2], 0, 0, 0);
            acc[c * 2 + kt2] = __builtin_amdgcn_mfma_f32_16x16x32_bf16(kf1, qf1, acc[c * 2 + kt2], 0, 0, 0);
        }
        __syncthreads();
    }
#undef STAGE_K

    // ---- softmax stats
    float mm = acc[0][0];
#pragma unroll
    for (int i = 0; i < 16; ++i) {
#pragma unroll
        for (int r = 0; r < 4; ++r) mm = fmaxf(mm, acc[i][r]);
    }
    mm = fmaxf(mm, __shfl_xor(mm, 16));
    mm = fmaxf(mm, __shfl_xor(mm, 32));
    if (lane < 16) red[w * 16 + lane] = mm;
    __syncthreads();

    float mx = red[q];
#pragma unroll
    for (int ww = 1; ww < 8; ++ww) mx = fmaxf(mx, red[ww * 16 + q]);

    float ssum = 0.f;
#pragma unroll
    for (int i = 0; i < 16; ++i) {
#pragma unroll
        for (int r = 0; r < 4; ++r) {
            const float p = __expf(acc[i][r] - mx);
            acc[i][r] = p;
            ssum += p;
        }
    }
    ssum += __shfl_xor(ssum, 16);
    ssum += __shfl_xor(ssum, 32);
    if (lane < 16) red[128 + w * 16 + lane] = ssum;
    __syncthreads();

    float tot = red[128 + q];
#pragma unroll
    for (int ww = 1; ww < 8; ++ww) tot += red[128 + ww * 16 + q];
    const float rinv = 1.f / tot;

    if constexpr (MODE == 3) {
        // QK+softmax-only ablation: keep chain live via small scratch write
        if (lane < 16)
            ((float*)Ctx)[((size_t)bh * 128 + qt) * 128 + w * 16 + q] = rinv + mx;
        return;
    }

    // ---- pack normalized P (bf16, swizzled): key c*256+w*32+kt2*16+g*4+r
#pragma unroll
    for (int i = 0; i < 16; ++i) {
        const int c2 = i >> 1, kt2 = i & 1;
        const float p0 = acc[i][0] * rinv;
        const float p1 = acc[i][1] * rinv;
        const float p2 = acc[i][2] * rinv;
        const float p3 = acc[i][3] * rinv;
        uint2 uu;
        uu.x = (uint)f2b(p0) | ((uint)f2b(p1) << 16);
        uu.y = (uint)f2b(p2) | ((uint)f2b(p3) << 16);
        *(uint2*)(Pb + q * 4096 + ((c2 * 512 + w * 64 + kt2 * 32 + g * 8) ^ swzP)) = uu;
    }
    __syncthreads();

    float* attn_base = attn_out + ((size_t)bh * SEQ + q0) * SEQ;

    if constexpr (MODE == 2) {
        // store-only ablation path (no PV)
#pragma unroll
        for (int it = 0; it < 16; ++it) {
            const int bofs = (w * 512 + lane * 8) ^ ((it & 7) << 4);
            const ushort4 p4 = *(const ushort4*)(Pb + it * 4096 + bofs);
            f32x4 o;
            o[0] = b2f(p4.x); o[1] = b2f(p4.y); o[2] = b2f(p4.z); o[3] = b2f(p4.w);
            __builtin_nontemporal_store(o, (f32x4*)&attn_base[(size_t)it * SEQ + w * 256 + lane * 4]);
        }
        return;
    }

    // ---- PV (pipelined): prefetch next chunk's B-frags; interleave attn store (MODE 0)
    const ushort* Vtp = Vt + (size_t)bh * DEPTH * SEQ;
    f32x4 ctx[4];
#pragma unroll
    for (int ni = 0; ni < 4; ++ni) ctx[ni] = (f32x4){0.f, 0.f, 0.f, 0.f};

    bf16x8 bfc[4], bfn[4];
#pragma unroll
    for (int ni = 0; ni < 4; ++ni)
        bfc[ni] = *(const bf16x8*)&Vtp[(size_t)(ni * 16 + q) * SEQ + (w * 32 + g * 8)];

#pragma unroll
    for (int c = 0; c < 8; ++c) {
        if (c < 7) {
            const int kofs = (c + 1) * 256 + w * 32 + g * 8;
#pragma unroll
            for (int ni = 0; ni < 4; ++ni)
                bfn[ni] = *(const bf16x8*)&Vtp[(size_t)(ni * 16 + q) * SEQ + kofs];
        }
        if constexpr (MODE == 0) {
#pragma unroll
            for (int s = 0; s < 2; ++s) {
                const int it = c * 2 + s;
                const int bofs = (w * 512 + lane * 8) ^ ((it & 7) << 4);
                const ushort4 p4 = *(const ushort4*)(Pb + it * 4096 + bofs);
                f32x4 o;
                o[0] = b2f(p4.x); o[1] = b2f(p4.y); o[2] = b2f(p4.z); o[3] = b2f(p4.w);
                __builtin_nontemporal_store(o, (f32x4*)&attn_base[(size_t)it * SEQ + w * 256 + lane * 4]);
            }
        }
        const bf16x8 af = *(const bf16x8*)(Pb + q * 4096 + ((c * 512 + w * 64 + g * 16) ^ swzP));
#pragma unroll
        for (int ni = 0; ni < 4; ++ni)
            ctx[ni] = __builtin_amdgcn_mfma_f32_16x16x32_bf16(af, bfc[ni], ctx[ni], 0, 0, 0);
        if (c < 7) {
#pragma unroll
            for (int ni = 0; ni < 4; ++ni) bfc[ni] = bfn[ni];
        }
    }
    __syncthreads();   // all P reads done; reuse P_lds as f32 partials [8][16][64]

    float* part = (float*)P_lds;
#pragma unroll
    for (int ni = 0; ni < 4; ++ni) {
#pragma unroll
        for (int r = 0; r < 4; ++r) {
            part[(w * 16 + g * 4 + r) * 64 + ni * 16 + q] = ctx[ni][r];
        }
    }
    __syncthreads();

#pragma unroll
    for (int idx = t; idx < 1024; idx += 512) {
        const int qq = idx >> 6, d = idx & 63;
        float s2 = 0.f;
#pragma unroll
        for (int ww = 0; ww < 8; ++ww) s2 += part[ww * 1024 + idx];
        Ctx[(size_t)(b * SEQ + q0 + qq) * DM + h * DEPTH + d] = f2b(s2);
    }
}

extern "C" void kernel_launch(void* const* d_in, const int* in_sizes, int n_in,
                              void* d_out, int out_size, void* d_ws, size_t ws_size,
                              hipStream_t stream) {
    const float* x  = (const float*)d_in[0];
    const float* wq = (const float*)d_in[1];
    const float* bq = (const float*)d_in[2];
    const float* wk = (const float*)d_in[3];
    const float* bk = (const float*)d_in[4];
    const float* wv = (const float*)d_in[5];
    const float* bv = (const float*)d_in[6];
    const float* wo = (const float*)d_in[7];
    const float* bo = (const float*)d_in[8];

    float* out  = (float*)d_out;                          // [2,2048,1024]
    float* attn = out + (size_t)MROWS * DM;               // [2,16,2048,2048] fp32

    ushort* ws  = (ushort*)d_ws;
    ushort* xb  = ws;                        // 4096x1024 bf16
    ushort* wqt = xb + (size_t)MROWS * DM;   // [wqt|wkt|wvt|wot] contiguous, each 1024x1024
    ushort* wot = wqt + (size_t)3 * DM * DM;
    ushort* Qh  = wot + (size_t)DM * DM;     // [Qh|Kh|Vh] contiguous, each 4096x1024 bf16
    ushort* Kh  = Qh + (size_t)MROWS * DM;
    ushort* Vh  = Kh + (size_t)MROWS * DM;
    ushort* cxb = Vh + (size_t)MROWS * DM;
    ushort* Vt  = cxb + (size_t)MROWS * DM;  // [32][64][2048] bf16
    ushort* ctxScratch = Vt + (size_t)BATCH * NH * DEPTH * SEQ;  // 8MB ablation sink

    convert_f32_bf16<<<dim3(MROWS * DM / 4 / 256), 256, 0, stream>>>(x, xb, MROWS * DM / 4);
    transpose_convert4<<<dim3(DM / 32, DM / 32, 4), 256, 0, stream>>>(wq, wk, wv, wo, wqt);

    gemm_qkv_mfma<<<dim3(3 * DM / 128, MROWS / 128), 256, 0, stream>>>(xb, wqt, bq, bk, bv, Qh);

    transpose_v<<<dim3(BATCH * NH, SEQ / 64), 256, 0, stream>>>(Vh, Vt);

    // --- ablation dummies at 4x grid (surface above ~330us fills); real kernel runs last ---
    attn_fused_kernel<3><<<dim3(SEQ / 16, 128), 512, 0, stream>>>(Qh, Kh, Vt, attn, ctxScratch);
    attn_fused_kernel<1><<<dim3(SEQ / 16, 128), 512, 0, stream>>>(Qh, Kh, Vt, attn, ctxScratch);
    attn_fused_kernel<2><<<dim3(SEQ / 16, 128), 512, 0, stream>>>(Qh, Kh, Vt, attn, ctxScratch);
    attn_fused_kernel<0><<<dim3(SEQ / 16, 32), 512, 0, stream>>>(Qh, Kh, Vt, attn, cxb);

    gemm_mfma_f32<<<dim3(DM / 128, MROWS / 128), 256, 0, stream>>>(cxb, wot, bo, out);
}

// Round 15
// 291.695 us; speedup vs baseline: 5.8206x; 5.8206x over previous
//
#include <hip/hip_runtime.h>
#include <hip/hip_bf16.h>

#define SEQ 2048
#define BATCH 2
#define NH 16
#define DM 1024
#define DEPTH 64
#define MROWS (BATCH * SEQ)   // 4096

typedef __attribute__((ext_vector_type(8))) short bf16x8;
typedef __attribute__((ext_vector_type(4))) float f32x4;

__device__ __forceinline__ float b2f(ushort u) {
    union { uint i; float f; } v; v.i = ((uint)u) << 16; return v.f;
}
__device__ __forceinline__ ushort f2b(float f) {
    __hip_bfloat16 h = __float2bfloat16(f);
    return *reinterpret_cast<ushort*>(&h);
}

__device__ __forceinline__ void gload_lds16(const void* g, void* l) {
    __builtin_amdgcn_global_load_lds((const __attribute__((address_space(1))) void*)g,
                                     (__attribute__((address_space(3))) void*)l, 16, 0, 0);
}

// ---------------- fp32 -> bf16 elementwise ----------------
__global__ __launch_bounds__(256) void convert_f32_bf16(const float* __restrict__ in,
                                                        ushort* __restrict__ outp, int n4) {
    int i = blockIdx.x * 256 + threadIdx.x;
    if (i < n4) {
        const float4 v = ((const float4*)in)[i];
        ushort4 o;
        o.x = f2b(v.x); o.y = f2b(v.y); o.z = f2b(v.z); o.w = f2b(v.w);
        ((ushort4*)outp)[i] = o;
    }
}

// ---------------- 4x fused: fp32 W[K][N] -> bf16 Wt[N][K], z selects weight ----------------
__global__ __launch_bounds__(256) void transpose_convert4(const float* __restrict__ w0,
                                                          const float* __restrict__ w1,
                                                          const float* __restrict__ w2,
                                                          const float* __restrict__ w3,
                                                          ushort* __restrict__ WtBase) {
    __shared__ float tile[32][33];
    const int z = blockIdx.z;
    const float* W = (z == 0) ? w0 : (z == 1) ? w1 : (z == 2) ? w2 : w3;
    ushort* Wt = WtBase + (size_t)z * DM * DM;
    const int bx = blockIdx.x * 32;  // n base
    const int by = blockIdx.y * 32;  // k base
    const int tx = threadIdx.x & 31, ty = threadIdx.x >> 5;
#pragma unroll
    for (int i = 0; i < 32; i += 8)
        tile[ty + i][tx] = W[(size_t)(by + ty + i) * DM + bx + tx];
    __syncthreads();
#pragma unroll
    for (int i = 0; i < 32; i += 8)
        Wt[(size_t)(bx + ty + i) * DM + by + tx] = f2b(tile[tx][ty + i]);
}

// ---------------- fused QKV GEMM: [4096,1024] @ [1024,3072] + bias -> bf16 ----------------
// Q bank (bank==0) is pre-scaled by 1/sqrt(DEPTH)=0.125 so attn skips the logit scale.
__global__ __launch_bounds__(256) void gemm_qkv_mfma(const ushort* __restrict__ A,
                                                     const ushort* __restrict__ WtAll,
                                                     const float* __restrict__ bq,
                                                     const float* __restrict__ bk,
                                                     const float* __restrict__ bv,
                                                     ushort* __restrict__ OutBase) {
    __shared__ __align__(16) ushort As[128 * 32];
    __shared__ __align__(16) ushort Bs[128 * 32];

    const int t    = threadIdx.x;
    const int lane = t & 63;
    const int w    = t >> 6;
    const int wr   = w >> 1, wc = w & 1;
    const int row0 = blockIdx.y * 128;
    const int col0 = blockIdx.x * 128;           // 0..2944
    const int bank = col0 >> 10;                 // 0,1,2
    const float* bias = (bank == 0) ? bq : (bank == 1) ? bk : bv;
    const float scale = (bank == 0) ? 0.125f : 1.0f;
    const int ccol0 = col0 & 1023;
    ushort* Cout = OutBase + (size_t)bank * MROWS * DM;

    f32x4 acc[4][4];
#pragma unroll
    for (int mi = 0; mi < 4; ++mi)
#pragma unroll
        for (int ni = 0; ni < 4; ++ni) acc[mi][ni] = (f32x4){0.f, 0.f, 0.f, 0.f};

    const int sr = t >> 2;
    const int sc = (t & 3) * 8;

    for (int k0 = 0; k0 < DM; k0 += 32) {
        gload_lds16(&A[(size_t)(row0 + sr) * DM + k0 + sc],          &As[w * 512]);
        gload_lds16(&A[(size_t)(row0 + 64 + sr) * DM + k0 + sc],     &As[2048 + w * 512]);
        gload_lds16(&WtAll[(size_t)(col0 + sr) * DM + k0 + sc],      &Bs[w * 512]);
        gload_lds16(&WtAll[(size_t)(col0 + 64 + sr) * DM + k0 + sc], &Bs[2048 + w * 512]);
        __syncthreads();

        bf16x8 af[4], bfr[4];
#pragma unroll
        for (int mi = 0; mi < 4; ++mi)
            af[mi] = *(const bf16x8*)&As[(wr * 64 + mi * 16 + (lane & 15)) * 32 + (lane >> 4) * 8];
#pragma unroll
        for (int ni = 0; ni < 4; ++ni)
            bfr[ni] = *(const bf16x8*)&Bs[(wc * 64 + ni * 16 + (lane & 15)) * 32 + (lane >> 4) * 8];
#pragma unroll
        for (int mi = 0; mi < 4; ++mi)
#pragma unroll
            for (int ni = 0; ni < 4; ++ni)
                acc[mi][ni] = __builtin_amdgcn_mfma_f32_16x16x32_bf16(af[mi], bfr[ni], acc[mi][ni], 0, 0, 0);
        __syncthreads();
    }

    float bb[4];
#pragma unroll
    for (int ni = 0; ni < 4; ++ni) bb[ni] = bias[ccol0 + wc * 64 + ni * 16 + (lane & 15)];

#pragma unroll
    for (int mi = 0; mi < 4; ++mi) {
        const int row = row0 + wr * 64 + mi * 16 + (lane >> 4) * 4;
#pragma unroll
        for (int ni = 0; ni < 4; ++ni) {
            const int col = ccol0 + wc * 64 + ni * 16 + (lane & 15);
#pragma unroll
            for (int r = 0; r < 4; ++r)
                Cout[(size_t)(row + r) * DM + col] = f2b((acc[mi][ni][r] + bb[ni]) * scale);
        }
    }
}

// ---------------- bf16 MFMA GEMM: C = A @ Wt^T + bias, fp32 out ----------------
__global__ __launch_bounds__(256) void gemm_mfma_f32(const ushort* __restrict__ A,
                                                     const ushort* __restrict__ Wt,
                                                     const float* __restrict__ bias,
                                                     float* __restrict__ Cout) {
    __shared__ __align__(16) ushort As[128 * 32];
    __shared__ __align__(16) ushort Bs[128 * 32];

    const int t    = threadIdx.x;
    const int lane = t & 63;
    const int w    = t >> 6;
    const int wr   = w >> 1, wc = w & 1;
    const int row0 = blockIdx.y * 128;
    const int col0 = blockIdx.x * 128;

    f32x4 acc[4][4];
#pragma unroll
    for (int mi = 0; mi < 4; ++mi)
#pragma unroll
        for (int ni = 0; ni < 4; ++ni) acc[mi][ni] = (f32x4){0.f, 0.f, 0.f, 0.f};

    const int sr = t >> 2;
    const int sc = (t & 3) * 8;

    for (int k0 = 0; k0 < DM; k0 += 32) {
        gload_lds16(&A[(size_t)(row0 + sr) * DM + k0 + sc],       &As[w * 512]);
        gload_lds16(&A[(size_t)(row0 + 64 + sr) * DM + k0 + sc],  &As[2048 + w * 512]);
        gload_lds16(&Wt[(size_t)(col0 + sr) * DM + k0 + sc],      &Bs[w * 512]);
        gload_lds16(&Wt[(size_t)(col0 + 64 + sr) * DM + k0 + sc], &Bs[2048 + w * 512]);
        __syncthreads();

        bf16x8 af[4], bfr[4];
#pragma unroll
        for (int mi = 0; mi < 4; ++mi)
            af[mi] = *(const bf16x8*)&As[(wr * 64 + mi * 16 + (lane & 15)) * 32 + (lane >> 4) * 8];
#pragma unroll
        for (int ni = 0; ni < 4; ++ni)
            bfr[ni] = *(const bf16x8*)&Bs[(wc * 64 + ni * 16 + (lane & 15)) * 32 + (lane >> 4) * 8];
#pragma unroll
        for (int mi = 0; mi < 4; ++mi)
#pragma unroll
            for (int ni = 0; ni < 4; ++ni)
                acc[mi][ni] = __builtin_amdgcn_mfma_f32_16x16x32_bf16(af[mi], bfr[ni], acc[mi][ni], 0, 0, 0);
        __syncthreads();
    }

    float bb[4];
#pragma unroll
    for (int ni = 0; ni < 4; ++ni) bb[ni] = bias[col0 + wc * 64 + ni * 16 + (lane & 15)];

#pragma unroll
    for (int mi = 0; mi < 4; ++mi) {
        const int row = row0 + wr * 64 + mi * 16 + (lane >> 4) * 4;
#pragma unroll
        for (int ni = 0; ni < 4; ++ni) {
            const int col = col0 + wc * 64 + ni * 16 + (lane & 15);
#pragma unroll
            for (int r = 0; r < 4; ++r)
                Cout[(size_t)(row + r) * DM + col] = acc[mi][ni][r] + bb[ni];
        }
    }
}

// ---------------- V transpose -> chunk-contiguous pre-swizzled Vt2 ----------------
// Vt2[bh][c=key/64][64 d][64 keys] bf16, 8KB per chunk, byte-in-row swizzled ^((d&7)<<4).
// Each 64-key chunk is contiguous -> PV staging is one fully coalesced gload per thread.
__global__ __launch_bounds__(256) void transpose_v(const ushort* __restrict__ Vh,
                                                   ushort* __restrict__ Vt2) {
    __shared__ ushort tile[64][80];
    const int t  = threadIdx.x;
    const int bh = blockIdx.x;
    const int c  = blockIdx.y;        // chunk index, keys [c*64, c*64+64)
    const int k0 = c * 64;
    const int b  = bh >> 4;
    const int h  = bh & 15;
    const size_t panel = (size_t)b * SEQ * DM + (size_t)h * DEPTH;

    {
        const int k = t >> 2, dc = (t & 3) * 16;
        const ushort* src = Vh + panel + (size_t)(k0 + k) * DM + dc;
        *(bf16x8*)&tile[k][dc]     = *(const bf16x8*)src;
        *(bf16x8*)&tile[k][dc + 8] = *(const bf16x8*)(src + 8);
    }
    __syncthreads();
    {
        const int d = t >> 2, kc = (t & 3) * 16;   // keys kc..kc+15 of row d
        bf16x8 o0, o1;
#pragma unroll
        for (int j = 0; j < 8; ++j) o0[j] = tile[kc + j][d];
#pragma unroll
        for (int j = 0; j < 8; ++j) o1[j] = tile[kc + 8 + j][d];
        char* base = (char*)Vt2 + ((size_t)bh * 32 + c) * 8192 + d * 128;
        const int sw = (d & 7) << 4;
        *(bf16x8*)(base + ((kc * 2) ^ sw))      = o0;
        *(bf16x8*)(base + ((kc * 2 + 16) ^ sw)) = o1;
    }
}

// ---------------- fused attention v8: K-staged QK + LDS-staged cooperative PV ----------
// 512 threads (8 waves), one (b,h) x 16 q-rows. LDS = P tile 64KB + V dbuf 16KB = 80KB
// (2 blocks/CU). Softmax stats overlay P_lds (K-staging area, dead post-QK; R11 pattern).
// PV: 32 chunks x 64 keys; per chunk wave w does ONE MFMA (kt=w&1 key-half, ni=w>>1
// d-block); V staged chunk-contiguous by 1 coalesced gload/thread, double-buffered.
__global__ __launch_bounds__(512, 2) void attn_fused_kernel(const ushort* __restrict__ Qh,
                                                            const ushort* __restrict__ Kh,
                                                            const ushort* __restrict__ Vt2,
                                                            float* __restrict__ attn_out,
                                                            ushort* __restrict__ Ctx) {
    __shared__ __align__(16) ushort P_lds[16 * 2048];   // 64 KB: K staging -> P tile -> partials
    __shared__ __align__(16) ushort V_lds[2 * 4096];    // 16 KB: V chunk double buffer

    const int t    = threadIdx.x;
    const int lane = t & 63;
    const int w    = t >> 6;          // 0..7
    const int qt   = blockIdx.x;      // fast axis -> panel-major dispatch
    const int bh   = blockIdx.y;
    const int b    = bh >> 4;
    const int h    = bh & 15;
    const int q0   = qt * 16;
    const int q    = lane & 15;
    const int g    = lane >> 4;       // 0..3
    const int swzP = (q & 7) << 4;

    const size_t panel = (size_t)b * SEQ * DM + (size_t)h * DEPTH;
    char* Pb = (char*)P_lds;
    char* Vb = (char*)V_lds;
    float* red = (float*)P_lds;       // stats overlay (K data dead when used)

    const ushort* Qrow = Qh + panel + (size_t)(q0 + q) * DM + g * 8;
    const bf16x8 qf0 = *(const bf16x8*)Qrow;
    const bf16x8 qf1 = *(const bf16x8*)(Qrow + 32);

    f32x4 acc[16];
#pragma unroll
    for (int i = 0; i < 16; ++i) acc[i] = (f32x4){0.f, 0.f, 0.f, 0.f};

    // ---- K staging (verified R13): chunk kc8 -> buffer kc8&1; swizzle on GLOBAL source col.
    const char* Ksrc = (const char*)(Kh + panel);
    const int srow  = t >> 3;
    const int scolb = ((t & 7) * 16) ^ ((srow & 7) << 4);
    char* wavedst = Pb + (t >> 6) * 1024;

#define STAGE_K(c)                                                                  \
    {                                                                               \
        char* dB = wavedst + ((c) & 1) * 32768;                                     \
        _Pragma("unroll")                                                           \
        for (int j = 0; j < 4; ++j) {                                               \
            const char* gp = Ksrc + (size_t)((c) * 256 + j * 64 + srow) * (DM * 2)  \
                             + scolb;                                               \
            gload_lds16(gp, dB + j * 8192);                                         \
        }                                                                           \
    }

    STAGE_K(0);
    __syncthreads();

#pragma unroll
    for (int c = 0; c < 8; ++c) {
        if (c < 7) STAGE_K(c + 1);
        const char* kb = Pb + (c & 1) * 32768;
#pragma unroll
        for (int kt2 = 0; kt2 < 2; ++kt2) {
            const char* rowp = kb + (w * 32 + kt2 * 16 + q) * 128;
            const bf16x8 kf0 = *(const bf16x8*)(rowp + ((g * 16) ^ swzP));
            const bf16x8 kf1 = *(const bf16x8*)(rowp + ((64 + g * 16) ^ swzP));
            acc[c * 2 + kt2] = __builtin_amdgcn_mfma_f32_16x16x32_bf16(kf0, qf0, acc[c * 2 + kt2], 0, 0, 0);
            acc[c * 2 + kt2] = __builtin_amdgcn_mfma_f32_16x16x32_bf16(kf1, qf1, acc[c * 2 + kt2], 0, 0, 0);
        }
        __syncthreads();
    }
#undef STAGE_K

    // ---- V prefetch: chunks 0,1 (land during softmax; barriers drain vmcnt)
    const char* Vsrc = (const char*)Vt2 + (size_t)bh * 262144;
#define STAGE_V(c)                                                                  \
    gload_lds16(Vsrc + (size_t)(c) * 8192 + t * 16,                                 \
                Vb + ((c) & 1) * 8192 + (t >> 6) * 1024)

    STAGE_V(0);
    STAGE_V(1);

    // ---- softmax stats (red overlays P_lds; K data dead)
    float mm = acc[0][0];
#pragma unroll
    for (int i = 0; i < 16; ++i) {
#pragma unroll
        for (int r = 0; r < 4; ++r) mm = fmaxf(mm, acc[i][r]);
    }
    mm = fmaxf(mm, __shfl_xor(mm, 16));
    mm = fmaxf(mm, __shfl_xor(mm, 32));
    if (lane < 16) red[w * 16 + lane] = mm;
    __syncthreads();

    float mx = red[q];
#pragma unroll
    for (int ww = 1; ww < 8; ++ww) mx = fmaxf(mx, red[ww * 16 + q]);
    __syncthreads();   // all waves read maxes before sums overwrite region? (separate idx; safe) — keep for order

    float ssum = 0.f;
#pragma unroll
    for (int i = 0; i < 16; ++i) {
#pragma unroll
        for (int r = 0; r < 4; ++r) {
            const float p = __expf(acc[i][r] - mx);
            acc[i][r] = p;
            ssum += p;
        }
    }
    ssum += __shfl_xor(ssum, 16);
    ssum += __shfl_xor(ssum, 32);
    if (lane < 16) red[128 + w * 16 + lane] = ssum;
    __syncthreads();

    float tot = red[128 + q];
#pragma unroll
    for (int ww = 1; ww < 8; ++ww) tot += red[128 + ww * 16 + q];
    const float rinv = 1.f / tot;
    __syncthreads();   // stats consumed -> P_lds writable for pack

    // ---- pack normalized P (bf16, swizzled): key kc8*256 + w*32 + kt2*16 + g*4 + r
#pragma unroll
    for (int i = 0; i < 16; ++i) {
        const int c2 = i >> 1, kt2 = i & 1;
        const float p0 = acc[i][0] * rinv;
        const float p1 = acc[i][1] * rinv;
        const float p2 = acc[i][2] * rinv;
        const float p3 = acc[i][3] * rinv;
        uint2 uu;
        uu.x = (uint)f2b(p0) | ((uint)f2b(p1) << 16);
        uu.y = (uint)f2b(p2) | ((uint)f2b(p3) << 16);
        *(uint2*)(Pb + q * 4096 + ((c2 * 512 + w * 64 + kt2 * 32 + g * 8) ^ swzP)) = uu;
    }
    __syncthreads();

    // ---- attn store: wave w writes rows 0..15, cols [w*256,+256); 1KB/inst, NT
    float* attn_base = attn_out + ((size_t)bh * SEQ + q0) * SEQ;
#pragma unroll
    for (int it = 0; it < 16; ++it) {
        const int bofs = (w * 512 + lane * 8) ^ ((it & 7) << 4);
        const ushort4 p4 = *(const ushort4*)(Pb + it * 4096 + bofs);
        f32x4 o;
        o[0] = b2f(p4.x); o[1] = b2f(p4.y); o[2] = b2f(p4.z); o[3] = b2f(p4.w);
        __builtin_nontemporal_store(o, (f32x4*)&attn_base[(size_t)it * SEQ + w * 256 + lane * 4]);
    }

    // ---- PV (cooperative, LDS-staged V): 32 chunks x 64 keys; wave w: kt=w&1, ni=w>>1
    const int kt   = w & 1;
    const int nni  = w >> 1;
    const int dloc = nni * 16 + q;                       // B-frag d row
    const int vofs = dloc * 128 + ((kt * 64 + g * 16) ^ ((q & 7) << 4));   // d&7 == q&7
    f32x4 ctx = (f32x4){0.f, 0.f, 0.f, 0.f};

#pragma unroll 4
    for (int c = 0; c < 32; ++c) {
        const bf16x8 af = *(const bf16x8*)(Pb + q * 4096 + ((c * 128 + kt * 64 + g * 16) ^ swzP));
        const bf16x8 bf = *(const bf16x8*)(Vb + (c & 1) * 8192 + vofs);
        ctx = __builtin_amdgcn_mfma_f32_16x16x32_bf16(af, bf, ctx, 0, 0, 0);
        __syncthreads();                    // reads of buf c&1 done; prefetch c+2 into it
        if (c + 2 < 32) STAGE_V(c + 2);
    }
#undef STAGE_V

    // ---- reduce: waves (2ni, 2ni+1) hold key-halves of d-block ni. C layout:
    // row = q = g*4+r, col = d_local = lane&15.
    float* part = (float*)P_lds;            // 8KB, P dead
#pragma unroll
    for (int r = 0; r < 4; ++r) {
        part[w * 256 + (g * 4 + r) * 16 + q] = ctx[r];
    }
    __syncthreads();

#pragma unroll
    for (int idx = t; idx < 1024; idx += 512) {
        const int qq = idx >> 6, d = idx & 63;
        const int pni = d >> 4, dl = d & 15;
        const float s2 = part[(2 * pni) * 256 + qq * 16 + dl] +
                         part[(2 * pni + 1) * 256 + qq * 16 + dl];
        Ctx[(size_t)(b * SEQ + q0 + qq) * DM + h * DEPTH + d] = f2b(s2);
    }
}

extern "C" void kernel_launch(void* const* d_in, const int* in_sizes, int n_in,
                              void* d_out, int out_size, void* d_ws, size_t ws_size,
                              hipStream_t stream) {
    const float* x  = (const float*)d_in[0];
    const float* wq = (const float*)d_in[1];
    const float* bq = (const float*)d_in[2];
    const float* wk = (const float*)d_in[3];
    const float* bk = (const float*)d_in[4];
    const float* wv = (const float*)d_in[5];
    const float* bv = (const float*)d_in[6];
    const float* wo = (const float*)d_in[7];
    const float* bo = (const float*)d_in[8];

    float* out  = (float*)d_out;                          // [2,2048,1024]
    float* attn = out + (size_t)MROWS * DM;               // [2,16,2048,2048] fp32

    ushort* ws  = (ushort*)d_ws;
    ushort* xb  = ws;                        // 4096x1024 bf16
    ushort* wqt = xb + (size_t)MROWS * DM;   // [wqt|wkt|wvt|wot] contiguous, each 1024x1024
    ushort* wot = wqt + (size_t)3 * DM * DM;
    ushort* Qh  = wot + (size_t)DM * DM;     // [Qh|Kh|Vh] contiguous, each 4096x1024 bf16
    ushort* Kh  = Qh + (size_t)MROWS * DM;
    ushort* Vh  = Kh + (size_t)MROWS * DM;
    ushort* cxb = Vh + (size_t)MROWS * DM;
    ushort* Vt2 = cxb + (size_t)MROWS * DM;  // [32 bh][32 c][64 d][64 k] bf16, 8MB

    convert_f32_bf16<<<dim3(MROWS * DM / 4 / 256), 256, 0, stream>>>(x, xb, MROWS * DM / 4);
    transpose_convert4<<<dim3(DM / 32, DM / 32, 4), 256, 0, stream>>>(wq, wk, wv, wo, wqt);

    gemm_qkv_mfma<<<dim3(3 * DM / 128, MROWS / 128), 256, 0, stream>>>(xb, wqt, bq, bk, bv, Qh);

    transpose_v<<<dim3(BATCH * NH, SEQ / 64), 256, 0, stream>>>(Vh, Vt2);

    attn_fused_kernel<<<dim3(SEQ / 16, BATCH * NH), 512, 0, stream>>>(Qh, Kh, Vt2, attn, cxb);

    gemm_mfma_f32<<<dim3(DM / 128, MROWS / 128), 256, 0, stream>>>(cxb, wot, bo, out);
}

// Round 16
// 222.586 us; speedup vs baseline: 7.6278x; 1.3105x over previous
//
#include <hip/hip_runtime.h>
#include <hip/hip_bf16.h>

#define SEQ 2048
#define BATCH 2
#define NH 16
#define DM 1024
#define DEPTH 64
#define MROWS (BATCH * SEQ)   // 4096

typedef __attribute__((ext_vector_type(8))) short bf16x8;
typedef __attribute__((ext_vector_type(4))) float f32x4;

__device__ __forceinline__ float b2f(ushort u) {
    union { uint i; float f; } v; v.i = ((uint)u) << 16; return v.f;
}
__device__ __forceinline__ ushort f2b(float f) {
    __hip_bfloat16 h = __float2bfloat16(f);
    return *reinterpret_cast<ushort*>(&h);
}

__device__ __forceinline__ void gload_lds16(const void* g, void* l) {
    __builtin_amdgcn_global_load_lds((const __attribute__((address_space(1))) void*)g,
                                     (__attribute__((address_space(3))) void*)l, 16, 0, 0);
}

// ---------------- fp32 -> bf16 elementwise ----------------
__global__ __launch_bounds__(256) void convert_f32_bf16(const float* __restrict__ in,
                                                        ushort* __restrict__ outp, int n4) {
    int i = blockIdx.x * 256 + threadIdx.x;
    if (i < n4) {
        const float4 v = ((const float4*)in)[i];
        ushort4 o;
        o.x = f2b(v.x); o.y = f2b(v.y); o.z = f2b(v.z); o.w = f2b(v.w);
        ((ushort4*)outp)[i] = o;
    }
}

// ---------------- 4x fused: fp32 W[K][N] -> bf16 Wt[N][K], z selects weight ----------------
__global__ __launch_bounds__(256) void transpose_convert4(const float* __restrict__ w0,
                                                          const float* __restrict__ w1,
                                                          const float* __restrict__ w2,
                                                          const float* __restrict__ w3,
                                                          ushort* __restrict__ WtBase) {
    __shared__ float tile[32][33];
    const int z = blockIdx.z;
    const float* W = (z == 0) ? w0 : (z == 1) ? w1 : (z == 2) ? w2 : w3;
    ushort* Wt = WtBase + (size_t)z * DM * DM;
    const int bx = blockIdx.x * 32;  // n base
    const int by = blockIdx.y * 32;  // k base
    const int tx = threadIdx.x & 31, ty = threadIdx.x >> 5;
#pragma unroll
    for (int i = 0; i < 32; i += 8)
        tile[ty + i][tx] = W[(size_t)(by + ty + i) * DM + bx + tx];
    __syncthreads();
#pragma unroll
    for (int i = 0; i < 32; i += 8)
        Wt[(size_t)(bx + ty + i) * DM + by + tx] = f2b(tile[tx][ty + i]);
}

// ---------------- fused QKV GEMM: [4096,1024] @ [1024,3072] + bias -> bf16 ----------------
// Q bank (bank==0) is pre-scaled by 1/sqrt(DEPTH)=0.125 so attn skips the logit scale.
__global__ __launch_bounds__(256) void gemm_qkv_mfma(const ushort* __restrict__ A,
                                                     const ushort* __restrict__ WtAll,
                                                     const float* __restrict__ bq,
                                                     const float* __restrict__ bk,
                                                     const float* __restrict__ bv,
                                                     ushort* __restrict__ OutBase) {
    __shared__ __align__(16) ushort As[128 * 32];
    __shared__ __align__(16) ushort Bs[128 * 32];

    const int t    = threadIdx.x;
    const int lane = t & 63;
    const int w    = t >> 6;
    const int wr   = w >> 1, wc = w & 1;
    const int row0 = blockIdx.y * 128;
    const int col0 = blockIdx.x * 128;           // 0..2944
    const int bank = col0 >> 10;                 // 0,1,2
    const float* bias = (bank == 0) ? bq : (bank == 1) ? bk : bv;
    const float scale = (bank == 0) ? 0.125f : 1.0f;
    const int ccol0 = col0 & 1023;
    ushort* Cout = OutBase + (size_t)bank * MROWS * DM;

    f32x4 acc[4][4];
#pragma unroll
    for (int mi = 0; mi < 4; ++mi)
#pragma unroll
        for (int ni = 0; ni < 4; ++ni) acc[mi][ni] = (f32x4){0.f, 0.f, 0.f, 0.f};

    const int sr = t >> 2;
    const int sc = (t & 3) * 8;

    for (int k0 = 0; k0 < DM; k0 += 32) {
        gload_lds16(&A[(size_t)(row0 + sr) * DM + k0 + sc],          &As[w * 512]);
        gload_lds16(&A[(size_t)(row0 + 64 + sr) * DM + k0 + sc],     &As[2048 + w * 512]);
        gload_lds16(&WtAll[(size_t)(col0 + sr) * DM + k0 + sc],      &Bs[w * 512]);
        gload_lds16(&WtAll[(size_t)(col0 + 64 + sr) * DM + k0 + sc], &Bs[2048 + w * 512]);
        __syncthreads();

        bf16x8 af[4], bfr[4];
#pragma unroll
        for (int mi = 0; mi < 4; ++mi)
            af[mi] = *(const bf16x8*)&As[(wr * 64 + mi * 16 + (lane & 15)) * 32 + (lane >> 4) * 8];
#pragma unroll
        for (int ni = 0; ni < 4; ++ni)
            bfr[ni] = *(const bf16x8*)&Bs[(wc * 64 + ni * 16 + (lane & 15)) * 32 + (lane >> 4) * 8];
#pragma unroll
        for (int mi = 0; mi < 4; ++mi)
#pragma unroll
            for (int ni = 0; ni < 4; ++ni)
                acc[mi][ni] = __builtin_amdgcn_mfma_f32_16x16x32_bf16(af[mi], bfr[ni], acc[mi][ni], 0, 0, 0);
        __syncthreads();
    }

    float bb[4];
#pragma unroll
    for (int ni = 0; ni < 4; ++ni) bb[ni] = bias[ccol0 + wc * 64 + ni * 16 + (lane & 15)];

#pragma unroll
    for (int mi = 0; mi < 4; ++mi) {
        const int row = row0 + wr * 64 + mi * 16 + (lane >> 4) * 4;
#pragma unroll
        for (int ni = 0; ni < 4; ++ni) {
            const int col = ccol0 + wc * 64 + ni * 16 + (lane & 15);
#pragma unroll
            for (int r = 0; r < 4; ++r)
                Cout[(size_t)(row + r) * DM + col] = f2b((acc[mi][ni][r] + bb[ni]) * scale);
        }
    }
}

// ---------------- bf16 MFMA GEMM: C = A @ Wt^T + bias, fp32 out ----------------
__global__ __launch_bounds__(256) void gemm_mfma_f32(const ushort* __restrict__ A,
                                                     const ushort* __restrict__ Wt,
                                                     const float* __restrict__ bias,
                                                     float* __restrict__ Cout) {
    __shared__ __align__(16) ushort As[128 * 32];
    __shared__ __align__(16) ushort Bs[128 * 32];

    const int t    = threadIdx.x;
    const int lane = t & 63;
    const int w    = t >> 6;
    const int wr   = w >> 1, wc = w & 1;
    const int row0 = blockIdx.y * 128;
    const int col0 = blockIdx.x * 128;

    f32x4 acc[4][4];
#pragma unroll
    for (int mi = 0; mi < 4; ++mi)
#pragma unroll
        for (int ni = 0; ni < 4; ++ni) acc[mi][ni] = (f32x4){0.f, 0.f, 0.f, 0.f};

    const int sr = t >> 2;
    const int sc = (t & 3) * 8;

    for (int k0 = 0; k0 < DM; k0 += 32) {
        gload_lds16(&A[(size_t)(row0 + sr) * DM + k0 + sc],       &As[w * 512]);
        gload_lds16(&A[(size_t)(row0 + 64 + sr) * DM + k0 + sc],  &As[2048 + w * 512]);
        gload_lds16(&Wt[(size_t)(col0 + sr) * DM + k0 + sc],      &Bs[w * 512]);
        gload_lds16(&Wt[(size_t)(col0 + 64 + sr) * DM + k0 + sc], &Bs[2048 + w * 512]);
        __syncthreads();

        bf16x8 af[4], bfr[4];
#pragma unroll
        for (int mi = 0; mi < 4; ++mi)
            af[mi] = *(const bf16x8*)&As[(wr * 64 + mi * 16 + (lane & 15)) * 32 + (lane >> 4) * 8];
#pragma unroll
        for (int ni = 0; ni < 4; ++ni)
            bfr[ni] = *(const bf16x8*)&Bs[(wc * 64 + ni * 16 + (lane & 15)) * 32 + (lane >> 4) * 8];
#pragma unroll
        for (int mi = 0; mi < 4; ++mi)
#pragma unroll
            for (int ni = 0; ni < 4; ++ni)
                acc[mi][ni] = __builtin_amdgcn_mfma_f32_16x16x32_bf16(af[mi], bfr[ni], acc[mi][ni], 0, 0, 0);
        __syncthreads();
    }

    float bb[4];
#pragma unroll
    for (int ni = 0; ni < 4; ++ni) bb[ni] = bias[col0 + wc * 64 + ni * 16 + (lane & 15)];

#pragma unroll
    for (int mi = 0; mi < 4; ++mi) {
        const int row = row0 + wr * 64 + mi * 16 + (lane >> 4) * 4;
#pragma unroll
        for (int ni = 0; ni < 4; ++ni) {
            const int col = col0 + wc * 64 + ni * 16 + (lane & 15);
#pragma unroll
            for (int r = 0; r < 4; ++r)
                Cout[(size_t)(row + r) * DM + col] = acc[mi][ni][r] + bb[ni];
        }
    }
}

// ---------------- V transpose -> fragment-linear Vt3 ----------------
// Vt3[bh][kc=key/32][ni=d/16][lane][8] bf16: V pre-arranged in exact MFMA B-fragment
// order. Lane l of fragment (kc,ni) holds V[key = kc*32+(l>>4)*8+j][d = ni*16+(l&15)].
// PV's per-wave fragment load becomes 1KB fully contiguous (no gather, no LDS).
__global__ __launch_bounds__(256) void transpose_v(const ushort* __restrict__ Vh,
                                                   ushort* __restrict__ Vt3) {
    __shared__ ushort tile[64][80];
    const int t  = threadIdx.x;
    const int bh = blockIdx.x;
    const int cc = blockIdx.y;        // 64-key group, keys [cc*64, cc*64+64)
    const int k0 = cc * 64;
    const int b  = bh >> 4;
    const int h  = bh & 15;
    const size_t panel = (size_t)b * SEQ * DM + (size_t)h * DEPTH;

    {
        const int k = t >> 2, dc = (t & 3) * 16;
        const ushort* src = Vh + panel + (size_t)(k0 + k) * DM + dc;
        *(bf16x8*)&tile[k][dc]     = *(const bf16x8*)src;
        *(bf16x8*)&tile[k][dc + 8] = *(const bf16x8*)(src + 8);
    }
    __syncthreads();
    {
        const int l  = t & 63;
        const int ni = t >> 6;        // 0..3
        const int kr = (l >> 4) * 8;  // key sub-row base
        const int dl = ni * 16 + (l & 15);
#pragma unroll
        for (int kh = 0; kh < 2; ++kh) {   // kc = cc*2 + kh
            bf16x8 o;
#pragma unroll
            for (int j = 0; j < 8; ++j) o[j] = tile[kh * 32 + kr + j][dl];
            char* dst = (char*)Vt3 +
                        (((size_t)bh * 64 + cc * 2 + kh) * 4 + ni) * 1024 + l * 16;
            *(bf16x8*)dst = o;
        }
    }
}

// ---------------- fused attention v9: K-staged QK (R13) + fragment-linear PV ----------
// 512 threads (8 waves), one (b,h) x 16 q-rows. Identical to the verified 277us R13
// kernel except PV reads V from Vt3 in fragment-linear order: per wave-inst 1KB
// contiguous, L2-hot, wave-private, zero barriers, zero LDS staging.
__global__ __launch_bounds__(512, 2) void attn_fused_kernel(const ushort* __restrict__ Qh,
                                                            const ushort* __restrict__ Kh,
                                                            const ushort* __restrict__ Vt3,
                                                            float* __restrict__ attn_out,
                                                            ushort* __restrict__ Ctx) {
    __shared__ __align__(16) ushort P_lds[16 * 2048];   // 64 KB: K staging -> P tile -> partials
    __shared__ float red[256];                          // softmax stats

    const int t    = threadIdx.x;
    const int lane = t & 63;
    const int w    = t >> 6;          // 0..7
    const int qt   = blockIdx.x;      // fast axis -> panel-major dispatch
    const int bh   = blockIdx.y;
    const int b    = bh >> 4;
    const int h    = bh & 15;
    const int q0   = qt * 16;
    const int q    = lane & 15;
    const int g    = lane >> 4;       // 0..3
    const int swzP = (q & 7) << 4;

    const size_t panel = (size_t)b * SEQ * DM + (size_t)h * DEPTH;
    char* Pb = (char*)P_lds;

    const ushort* Qrow = Qh + panel + (size_t)(q0 + q) * DM + g * 8;
    const bf16x8 qf0 = *(const bf16x8*)Qrow;
    const bf16x8 qf1 = *(const bf16x8*)(Qrow + 32);

    f32x4 acc[16];
#pragma unroll
    for (int i = 0; i < 16; ++i) acc[i] = (f32x4){0.f, 0.f, 0.f, 0.f};

    // ---- K staging (verified R13): chunk c -> buffer c&1; swizzle on GLOBAL source col.
    const char* Ksrc = (const char*)(Kh + panel);
    const int srow  = t >> 3;
    const int scolb = ((t & 7) * 16) ^ ((srow & 7) << 4);
    char* wavedst = Pb + (t >> 6) * 1024;

#define STAGE_K(c)                                                                  \
    {                                                                               \
        char* dB = wavedst + ((c) & 1) * 32768;                                     \
        _Pragma("unroll")                                                           \
        for (int j = 0; j < 4; ++j) {                                               \
            const char* gp = Ksrc + (size_t)((c) * 256 + j * 64 + srow) * (DM * 2)  \
                             + scolb;                                               \
            gload_lds16(gp, dB + j * 8192);                                         \
        }                                                                           \
    }

    STAGE_K(0);
    __syncthreads();

#pragma unroll
    for (int c = 0; c < 8; ++c) {
        if (c < 7) STAGE_K(c + 1);
        const char* kb = Pb + (c & 1) * 32768;
#pragma unroll
        for (int kt2 = 0; kt2 < 2; ++kt2) {
            const char* rowp = kb + (w * 32 + kt2 * 16 + q) * 128;
            const bf16x8 kf0 = *(const bf16x8*)(rowp + ((g * 16) ^ swzP));
            const bf16x8 kf1 = *(const bf16x8*)(rowp + ((64 + g * 16) ^ swzP));
            acc[c * 2 + kt2] = __builtin_amdgcn_mfma_f32_16x16x32_bf16(kf0, qf0, acc[c * 2 + kt2], 0, 0, 0);
            acc[c * 2 + kt2] = __builtin_amdgcn_mfma_f32_16x16x32_bf16(kf1, qf1, acc[c * 2 + kt2], 0, 0, 0);
        }
        __syncthreads();
    }
#undef STAGE_K

    // ---- softmax stats
    float mm = acc[0][0];
#pragma unroll
    for (int i = 0; i < 16; ++i) {
#pragma unroll
        for (int r = 0; r < 4; ++r) mm = fmaxf(mm, acc[i][r]);
    }
    mm = fmaxf(mm, __shfl_xor(mm, 16));
    mm = fmaxf(mm, __shfl_xor(mm, 32));
    if (lane < 16) red[w * 16 + lane] = mm;
    __syncthreads();

    float mx = red[q];
#pragma unroll
    for (int ww = 1; ww < 8; ++ww) mx = fmaxf(mx, red[ww * 16 + q]);

    float ssum = 0.f;
#pragma unroll
    for (int i = 0; i < 16; ++i) {
#pragma unroll
        for (int r = 0; r < 4; ++r) {
            const float p = __expf(acc[i][r] - mx);
            acc[i][r] = p;
            ssum += p;
        }
    }
    ssum += __shfl_xor(ssum, 16);
    ssum += __shfl_xor(ssum, 32);
    if (lane < 16) red[128 + w * 16 + lane] = ssum;
    __syncthreads();

    float tot = red[128 + q];
#pragma unroll
    for (int ww = 1; ww < 8; ++ww) tot += red[128 + ww * 16 + q];
    const float rinv = 1.f / tot;

    // ---- pack normalized P (bf16, swizzled): key c*256 + w*32 + kt2*16 + g*4 + r
#pragma unroll
    for (int i = 0; i < 16; ++i) {
        const int c2 = i >> 1, kt2 = i & 1;
        const float p0 = acc[i][0] * rinv;
        const float p1 = acc[i][1] * rinv;
        const float p2 = acc[i][2] * rinv;
        const float p3 = acc[i][3] * rinv;
        uint2 uu;
        uu.x = (uint)f2b(p0) | ((uint)f2b(p1) << 16);
        uu.y = (uint)f2b(p2) | ((uint)f2b(p3) << 16);
        *(uint2*)(Pb + q * 4096 + ((c2 * 512 + w * 64 + kt2 * 32 + g * 8) ^ swzP)) = uu;
    }
    __syncthreads();

    // ---- attn store: wave w writes rows 0..15, cols [w*256,+256); 1KB/inst, NT
    float* attn_base = attn_out + ((size_t)bh * SEQ + q0) * SEQ;
#pragma unroll
    for (int it = 0; it < 16; ++it) {
        const int bofs = (w * 512 + lane * 8) ^ ((it & 7) << 4);
        const ushort4 p4 = *(const ushort4*)(Pb + it * 4096 + bofs);
        f32x4 o;
        o[0] = b2f(p4.x); o[1] = b2f(p4.y); o[2] = b2f(p4.z); o[3] = b2f(p4.w);
        __builtin_nontemporal_store(o, (f32x4*)&attn_base[(size_t)it * SEQ + w * 256 + lane * 4]);
    }

    // ---- PV: wave w over keys {c*256 + w*32 .. +32}; V from fragment-linear Vt3.
    // Per (c,ni): one 1KB-contiguous wave-load + one MFMA. No barriers, no staging.
    const char* Vf = (const char*)Vt3 + (size_t)bh * 262144;   // 64kc x 4ni x 1KB
    f32x4 ctx[4];
#pragma unroll
    for (int ni = 0; ni < 4; ++ni) ctx[ni] = (f32x4){0.f, 0.f, 0.f, 0.f};

#pragma unroll
    for (int c = 0; c < 8; ++c) {
        const bf16x8 af = *(const bf16x8*)(Pb + q * 4096 + ((c * 512 + w * 64 + g * 16) ^ swzP));
        const char* fb = Vf + (size_t)((c * 8 + w) * 4) * 1024 + lane * 16;
#pragma unroll
        for (int ni = 0; ni < 4; ++ni) {
            const bf16x8 bfr = *(const bf16x8*)(fb + ni * 1024);
            ctx[ni] = __builtin_amdgcn_mfma_f32_16x16x32_bf16(af, bfr, ctx[ni], 0, 0, 0);
        }
    }
    __syncthreads();   // all P reads done; reuse P_lds as f32 partials [8][16][64]

    float* part = (float*)P_lds;
#pragma unroll
    for (int ni = 0; ni < 4; ++ni) {
#pragma unroll
        for (int r = 0; r < 4; ++r) {
            part[(w * 16 + g * 4 + r) * 64 + ni * 16 + q] = ctx[ni][r];
        }
    }
    __syncthreads();

#pragma unroll
    for (int idx = t; idx < 1024; idx += 512) {
        const int qq = idx >> 6, d = idx & 63;
        float s2 = 0.f;
#pragma unroll
        for (int ww = 0; ww < 8; ++ww) s2 += part[ww * 1024 + idx];
        Ctx[(size_t)(b * SEQ + q0 + qq) * DM + h * DEPTH + d] = f2b(s2);
    }
}

extern "C" void kernel_launch(void* const* d_in, const int* in_sizes, int n_in,
                              void* d_out, int out_size, void* d_ws, size_t ws_size,
                              hipStream_t stream) {
    const float* x  = (const float*)d_in[0];
    const float* wq = (const float*)d_in[1];
    const float* bq = (const float*)d_in[2];
    const float* wk = (const float*)d_in[3];
    const float* bk = (const float*)d_in[4];
    const float* wv = (const float*)d_in[5];
    const float* bv = (const float*)d_in[6];
    const float* wo = (const float*)d_in[7];
    const float* bo = (const float*)d_in[8];

    float* out  = (float*)d_out;                          // [2,2048,1024]
    float* attn = out + (size_t)MROWS * DM;               // [2,16,2048,2048] fp32

    ushort* ws  = (ushort*)d_ws;
    ushort* xb  = ws;                        // 4096x1024 bf16
    ushort* wqt = xb + (size_t)MROWS * DM;   // [wqt|wkt|wvt|wot] contiguous, each 1024x1024
    ushort* wot = wqt + (size_t)3 * DM * DM;
    ushort* Qh  = wot + (size_t)DM * DM;     // [Qh|Kh|Vh] contiguous, each 4096x1024 bf16
    ushort* Kh  = Qh + (size_t)MROWS * DM;
    ushort* Vh  = Kh + (size_t)MROWS * DM;
    ushort* cxb = Vh + (size_t)MROWS * DM;
    ushort* Vt3 = cxb + (size_t)MROWS * DM;  // [32 bh][64 kc][4 ni][64 lane][8] bf16, 8MB

    convert_f32_bf16<<<dim3(MROWS * DM / 4 / 256), 256, 0, stream>>>(x, xb, MROWS * DM / 4);
    transpose_convert4<<<dim3(DM / 32, DM / 32, 4), 256, 0, stream>>>(wq, wk, wv, wo, wqt);

    gemm_qkv_mfma<<<dim3(3 * DM / 128, MROWS / 128), 256, 0, stream>>>(xb, wqt, bq, bk, bv, Qh);

    transpose_v<<<dim3(BATCH * NH, SEQ / 64), 256, 0, stream>>>(Vh, Vt3);

    attn_fused_kernel<<<dim3(SEQ / 16, BATCH * NH), 512, 0, stream>>>(Qh, Kh, Vt3, attn, cxb);

    gemm_mfma_f32<<<dim3(DM / 128, MROWS / 128), 256, 0, stream>>>(cxb, wot, bo, out);
}

// Round 17
// 221.970 us; speedup vs baseline: 7.6489x; 1.0028x over previous
//
#include <hip/hip_runtime.h>
#include <hip/hip_bf16.h>

#define SEQ 2048
#define BATCH 2
#define NH 16
#define DM 1024
#define DEPTH 64
#define MROWS (BATCH * SEQ)   // 4096

typedef __attribute__((ext_vector_type(8))) short bf16x8;
typedef __attribute__((ext_vector_type(4))) float f32x4;

__device__ __forceinline__ float b2f(ushort u) {
    union { uint i; float f; } v; v.i = ((uint)u) << 16; return v.f;
}
__device__ __forceinline__ ushort f2b(float f) {
    __hip_bfloat16 h = __float2bfloat16(f);
    return *reinterpret_cast<ushort*>(&h);
}

__device__ __forceinline__ void gload_lds16(const void* g, void* l) {
    __builtin_amdgcn_global_load_lds((const __attribute__((address_space(1))) void*)g,
                                     (__attribute__((address_space(3))) void*)l, 16, 0, 0);
}

// ---------------- fp32 -> bf16 elementwise ----------------
__global__ __launch_bounds__(256) void convert_f32_bf16(const float* __restrict__ in,
                                                        ushort* __restrict__ outp, int n4) {
    int i = blockIdx.x * 256 + threadIdx.x;
    if (i < n4) {
        const float4 v = ((const float4*)in)[i];
        ushort4 o;
        o.x = f2b(v.x); o.y = f2b(v.y); o.z = f2b(v.z); o.w = f2b(v.w);
        ((ushort4*)outp)[i] = o;
    }
}

// ---------------- 4x fused: fp32 W[K][N] -> bf16 Wt[N][K], z selects weight ----------------
__global__ __launch_bounds__(256) void transpose_convert4(const float* __restrict__ w0,
                                                          const float* __restrict__ w1,
                                                          const float* __restrict__ w2,
                                                          const float* __restrict__ w3,
                                                          ushort* __restrict__ WtBase) {
    __shared__ float tile[32][33];
    const int z = blockIdx.z;
    const float* W = (z == 0) ? w0 : (z == 1) ? w1 : (z == 2) ? w2 : w3;
    ushort* Wt = WtBase + (size_t)z * DM * DM;
    const int bx = blockIdx.x * 32;  // n base
    const int by = blockIdx.y * 32;  // k base
    const int tx = threadIdx.x & 31, ty = threadIdx.x >> 5;
#pragma unroll
    for (int i = 0; i < 32; i += 8)
        tile[ty + i][tx] = W[(size_t)(by + ty + i) * DM + bx + tx];
    __syncthreads();
#pragma unroll
    for (int i = 0; i < 32; i += 8)
        Wt[(size_t)(bx + ty + i) * DM + by + tx] = f2b(tile[tx][ty + i]);
}

// ---------------- fused QKV GEMM: [4096,1024] @ [1024,3072] + bias -> bf16 ----------------
// Q bank (bank==0) is pre-scaled by 1/sqrt(DEPTH)=0.125 so attn skips the logit scale.
__global__ __launch_bounds__(256) void gemm_qkv_mfma(const ushort* __restrict__ A,
                                                     const ushort* __restrict__ WtAll,
                                                     const float* __restrict__ bq,
                                                     const float* __restrict__ bk,
                                                     const float* __restrict__ bv,
                                                     ushort* __restrict__ OutBase) {
    __shared__ __align__(16) ushort As[128 * 32];
    __shared__ __align__(16) ushort Bs[128 * 32];

    const int t    = threadIdx.x;
    const int lane = t & 63;
    const int w    = t >> 6;
    const int wr   = w >> 1, wc = w & 1;
    const int row0 = blockIdx.y * 128;
    const int col0 = blockIdx.x * 128;           // 0..2944
    const int bank = col0 >> 10;                 // 0,1,2
    const float* bias = (bank == 0) ? bq : (bank == 1) ? bk : bv;
    const float scale = (bank == 0) ? 0.125f : 1.0f;
    const int ccol0 = col0 & 1023;
    ushort* Cout = OutBase + (size_t)bank * MROWS * DM;

    f32x4 acc[4][4];
#pragma unroll
    for (int mi = 0; mi < 4; ++mi)
#pragma unroll
        for (int ni = 0; ni < 4; ++ni) acc[mi][ni] = (f32x4){0.f, 0.f, 0.f, 0.f};

    const int sr = t >> 2;
    const int sc = (t & 3) * 8;

    for (int k0 = 0; k0 < DM; k0 += 32) {
        gload_lds16(&A[(size_t)(row0 + sr) * DM + k0 + sc],          &As[w * 512]);
        gload_lds16(&A[(size_t)(row0 + 64 + sr) * DM + k0 + sc],     &As[2048 + w * 512]);
        gload_lds16(&WtAll[(size_t)(col0 + sr) * DM + k0 + sc],      &Bs[w * 512]);
        gload_lds16(&WtAll[(size_t)(col0 + 64 + sr) * DM + k0 + sc], &Bs[2048 + w * 512]);
        __syncthreads();

        bf16x8 af[4], bfr[4];
#pragma unroll
        for (int mi = 0; mi < 4; ++mi)
            af[mi] = *(const bf16x8*)&As[(wr * 64 + mi * 16 + (lane & 15)) * 32 + (lane >> 4) * 8];
#pragma unroll
        for (int ni = 0; ni < 4; ++ni)
            bfr[ni] = *(const bf16x8*)&Bs[(wc * 64 + ni * 16 + (lane & 15)) * 32 + (lane >> 4) * 8];
#pragma unroll
        for (int mi = 0; mi < 4; ++mi)
#pragma unroll
            for (int ni = 0; ni < 4; ++ni)
                acc[mi][ni] = __builtin_amdgcn_mfma_f32_16x16x32_bf16(af[mi], bfr[ni], acc[mi][ni], 0, 0, 0);
        __syncthreads();
    }

    float bb[4];
#pragma unroll
    for (int ni = 0; ni < 4; ++ni) bb[ni] = bias[ccol0 + wc * 64 + ni * 16 + (lane & 15)];

#pragma unroll
    for (int mi = 0; mi < 4; ++mi) {
        const int row = row0 + wr * 64 + mi * 16 + (lane >> 4) * 4;
#pragma unroll
        for (int ni = 0; ni < 4; ++ni) {
            const int col = ccol0 + wc * 64 + ni * 16 + (lane & 15);
#pragma unroll
            for (int r = 0; r < 4; ++r)
                Cout[(size_t)(row + r) * DM + col] = f2b((acc[mi][ni][r] + bb[ni]) * scale);
        }
    }
}

// ---------------- bf16 MFMA GEMM: C = A @ Wt^T + bias, fp32 out ----------------
__global__ __launch_bounds__(256) void gemm_mfma_f32(const ushort* __restrict__ A,
                                                     const ushort* __restrict__ Wt,
                                                     const float* __restrict__ bias,
                                                     float* __restrict__ Cout) {
    __shared__ __align__(16) ushort As[128 * 32];
    __shared__ __align__(16) ushort Bs[128 * 32];

    const int t    = threadIdx.x;
    const int lane = t & 63;
    const int w    = t >> 6;
    const int wr   = w >> 1, wc = w & 1;
    const int row0 = blockIdx.y * 128;
    const int col0 = blockIdx.x * 128;

    f32x4 acc[4][4];
#pragma unroll
    for (int mi = 0; mi < 4; ++mi)
#pragma unroll
        for (int ni = 0; ni < 4; ++ni) acc[mi][ni] = (f32x4){0.f, 0.f, 0.f, 0.f};

    const int sr = t >> 2;
    const int sc = (t & 3) * 8;

    for (int k0 = 0; k0 < DM; k0 += 32) {
        gload_lds16(&A[(size_t)(row0 + sr) * DM + k0 + sc],       &As[w * 512]);
        gload_lds16(&A[(size_t)(row0 + 64 + sr) * DM + k0 + sc],  &As[2048 + w * 512]);
        gload_lds16(&Wt[(size_t)(col0 + sr) * DM + k0 + sc],      &Bs[w * 512]);
        gload_lds16(&Wt[(size_t)(col0 + 64 + sr) * DM + k0 + sc], &Bs[2048 + w * 512]);
        __syncthreads();

        bf16x8 af[4], bfr[4];
#pragma unroll
        for (int mi = 0; mi < 4; ++mi)
            af[mi] = *(const bf16x8*)&As[(wr * 64 + mi * 16 + (lane & 15)) * 32 + (lane >> 4) * 8];
#pragma unroll
        for (int ni = 0; ni < 4; ++ni)
            bfr[ni] = *(const bf16x8*)&Bs[(wc * 64 + ni * 16 + (lane & 15)) * 32 + (lane >> 4) * 8];
#pragma unroll
        for (int mi = 0; mi < 4; ++mi)
#pragma unroll
            for (int ni = 0; ni < 4; ++ni)
                acc[mi][ni] = __builtin_amdgcn_mfma_f32_16x16x32_bf16(af[mi], bfr[ni], acc[mi][ni], 0, 0, 0);
        __syncthreads();
    }

    float bb[4];
#pragma unroll
    for (int ni = 0; ni < 4; ++ni) bb[ni] = bias[col0 + wc * 64 + ni * 16 + (lane & 15)];

#pragma unroll
    for (int mi = 0; mi < 4; ++mi) {
        const int row = row0 + wr * 64 + mi * 16 + (lane >> 4) * 4;
#pragma unroll
        for (int ni = 0; ni < 4; ++ni) {
            const int col = col0 + wc * 64 + ni * 16 + (lane & 15);
#pragma unroll
            for (int r = 0; r < 4; ++r)
                Cout[(size_t)(row + r) * DM + col] = acc[mi][ni][r] + bb[ni];
        }
    }
}

// ---------------- V transpose -> fragment-linear Vt3 (verified R16) ----------------
// Vt3[bh][kc=key/32][ni=d/16][lane][8] bf16: exact MFMA B-fragment order.
__global__ __launch_bounds__(256) void transpose_v(const ushort* __restrict__ Vh,
                                                   ushort* __restrict__ Vt3) {
    __shared__ ushort tile[64][80];
    const int t  = threadIdx.x;
    const int bh = blockIdx.x;
    const int cc = blockIdx.y;        // 64-key group
    const int k0 = cc * 64;
    const int b  = bh >> 4;
    const int h  = bh & 15;
    const size_t panel = (size_t)b * SEQ * DM + (size_t)h * DEPTH;

    {
        const int k = t >> 2, dc = (t & 3) * 16;
        const ushort* src = Vh + panel + (size_t)(k0 + k) * DM + dc;
        *(bf16x8*)&tile[k][dc]     = *(const bf16x8*)src;
        *(bf16x8*)&tile[k][dc + 8] = *(const bf16x8*)(src + 8);
    }
    __syncthreads();
    {
        const int l  = t & 63;
        const int ni = t >> 6;        // 0..3
        const int kr = (l >> 4) * 8;
        const int dl = ni * 16 + (l & 15);
#pragma unroll
        for (int kh = 0; kh < 2; ++kh) {
            bf16x8 o;
#pragma unroll
            for (int j = 0; j < 8; ++j) o[j] = tile[kh * 32 + kr + j][dl];
            char* dst = (char*)Vt3 +
                        (((size_t)bh * 64 + cc * 2 + kh) * 4 + ni) * 1024 + l * 16;
            *(bf16x8*)dst = o;
        }
    }
}

// ---------------- fused attention v10: counted-vmcnt K pipeline (T4) + frag-linear PV ------
// Identical to verified R16 except the QK staging loop: raw s_barrier + counted
// s_waitcnt vmcnt(4) — stage(c+1)'s loads stay in flight across the barrier instead of
// being drained by __syncthreads' implicit vmcnt(0). Two barriers/chunk, no full drains.
// Race audit: trailing barrier of iter c-1 precedes stage(c+1) issue in all waves, and
// buffer (c+1)&1 was last read in compute(c-1) -> no overwrite race.
__global__ __launch_bounds__(512, 2) void attn_fused_kernel(const ushort* __restrict__ Qh,
                                                            const ushort* __restrict__ Kh,
                                                            const ushort* __restrict__ Vt3,
                                                            float* __restrict__ attn_out,
                                                            ushort* __restrict__ Ctx) {
    __shared__ __align__(16) ushort P_lds[16 * 2048];   // 64 KB: K staging -> P tile -> partials
    __shared__ float red[256];                          // softmax stats

    const int t    = threadIdx.x;
    const int lane = t & 63;
    const int w    = t >> 6;          // 0..7
    const int qt   = blockIdx.x;      // fast axis -> panel-major dispatch
    const int bh   = blockIdx.y;
    const int b    = bh >> 4;
    const int h    = bh & 15;
    const int q0   = qt * 16;
    const int q    = lane & 15;
    const int g    = lane >> 4;       // 0..3
    const int swzP = (q & 7) << 4;

    const size_t panel = (size_t)b * SEQ * DM + (size_t)h * DEPTH;
    char* Pb = (char*)P_lds;

    const ushort* Qrow = Qh + panel + (size_t)(q0 + q) * DM + g * 8;
    const bf16x8 qf0 = *(const bf16x8*)Qrow;
    const bf16x8 qf1 = *(const bf16x8*)(Qrow + 32);

    f32x4 acc[16];
#pragma unroll
    for (int i = 0; i < 16; ++i) acc[i] = (f32x4){0.f, 0.f, 0.f, 0.f};

    // ---- K staging (R13 layout): chunk c -> buffer c&1; swizzle on GLOBAL source col.
    const char* Ksrc = (const char*)(Kh + panel);
    const int srow  = t >> 3;
    const int scolb = ((t & 7) * 16) ^ ((srow & 7) << 4);
    char* wavedst = Pb + (t >> 6) * 1024;

#define STAGE_K(c)                                                                  \
    {                                                                               \
        char* dB = wavedst + ((c) & 1) * 32768;                                     \
        _Pragma("unroll")                                                           \
        for (int j = 0; j < 4; ++j) {                                               \
            const char* gp = Ksrc + (size_t)((c) * 256 + j * 64 + srow) * (DM * 2)  \
                             + scolb;                                               \
            gload_lds16(gp, dB + j * 8192);                                         \
        }                                                                           \
    }

    STAGE_K(0);   // 4 loads in flight

#pragma unroll
    for (int c = 0; c < 8; ++c) {
        if (c < 7) {
            STAGE_K(c + 1);   // +4 loads (other buffer)
            // wait ONLY stage(c)'s 4 oldest loads; stage(c+1) stays in flight
            asm volatile("s_waitcnt vmcnt(4)\n\ts_barrier" ::: "memory");
        } else {
            asm volatile("s_waitcnt vmcnt(0)\n\ts_barrier" ::: "memory");
        }
        const char* kb = Pb + (c & 1) * 32768;
#pragma unroll
        for (int kt2 = 0; kt2 < 2; ++kt2) {
            const char* rowp = kb + (w * 32 + kt2 * 16 + q) * 128;
            const bf16x8 kf0 = *(const bf16x8*)(rowp + ((g * 16) ^ swzP));
            const bf16x8 kf1 = *(const bf16x8*)(rowp + ((64 + g * 16) ^ swzP));
            acc[c * 2 + kt2] = __builtin_amdgcn_mfma_f32_16x16x32_bf16(kf0, qf0, acc[c * 2 + kt2], 0, 0, 0);
            acc[c * 2 + kt2] = __builtin_amdgcn_mfma_f32_16x16x32_bf16(kf1, qf1, acc[c * 2 + kt2], 0, 0, 0);
        }
        // all waves done reading buffer c&1 before next iteration's stage(c+2) rewrites it
        asm volatile("s_barrier" ::: "memory");
    }
#undef STAGE_K

    // ---- softmax stats
    float mm = acc[0][0];
#pragma unroll
    for (int i = 0; i < 16; ++i) {
#pragma unroll
        for (int r = 0; r < 4; ++r) mm = fmaxf(mm, acc[i][r]);
    }
    mm = fmaxf(mm, __shfl_xor(mm, 16));
    mm = fmaxf(mm, __shfl_xor(mm, 32));
    if (lane < 16) red[w * 16 + lane] = mm;
    __syncthreads();

    float mx = red[q];
#pragma unroll
    for (int ww = 1; ww < 8; ++ww) mx = fmaxf(mx, red[ww * 16 + q]);

    float ssum = 0.f;
#pragma unroll
    for (int i = 0; i < 16; ++i) {
#pragma unroll
        for (int r = 0; r < 4; ++r) {
            const float p = __expf(acc[i][r] - mx);
            acc[i][r] = p;
            ssum += p;
        }
    }
    ssum += __shfl_xor(ssum, 16);
    ssum += __shfl_xor(ssum, 32);
    if (lane < 16) red[128 + w * 16 + lane] = ssum;
    __syncthreads();

    float tot = red[128 + q];
#pragma unroll
    for (int ww = 1; ww < 8; ++ww) tot += red[128 + ww * 16 + q];
    const float rinv = 1.f / tot;

    // ---- pack normalized P (bf16, swizzled): key c*256 + w*32 + kt2*16 + g*4 + r
#pragma unroll
    for (int i = 0; i < 16; ++i) {
        const int c2 = i >> 1, kt2 = i & 1;
        const float p0 = acc[i][0] * rinv;
        const float p1 = acc[i][1] * rinv;
        const float p2 = acc[i][2] * rinv;
        const float p3 = acc[i][3] * rinv;
        uint2 uu;
        uu.x = (uint)f2b(p0) | ((uint)f2b(p1) << 16);
        uu.y = (uint)f2b(p2) | ((uint)f2b(p3) << 16);
        *(uint2*)(Pb + q * 4096 + ((c2 * 512 + w * 64 + kt2 * 32 + g * 8) ^ swzP)) = uu;
    }
    __syncthreads();

    // ---- attn store: wave w writes rows 0..15, cols [w*256,+256); 1KB/inst, NT
    float* attn_base = attn_out + ((size_t)bh * SEQ + q0) * SEQ;
#pragma unroll
    for (int it = 0; it < 16; ++it) {
        const int bofs = (w * 512 + lane * 8) ^ ((it & 7) << 4);
        const ushort4 p4 = *(const ushort4*)(Pb + it * 4096 + bofs);
        f32x4 o;
        o[0] = b2f(p4.x); o[1] = b2f(p4.y); o[2] = b2f(p4.z); o[3] = b2f(p4.w);
        __builtin_nontemporal_store(o, (f32x4*)&attn_base[(size_t)it * SEQ + w * 256 + lane * 4]);
    }

    // ---- PV: wave w over keys {c*256 + w*32 .. +32}; V from fragment-linear Vt3.
    const char* Vf = (const char*)Vt3 + (size_t)bh * 262144;   // 64kc x 4ni x 1KB
    f32x4 ctx[4];
#pragma unroll
    for (int ni = 0; ni < 4; ++ni) ctx[ni] = (f32x4){0.f, 0.f, 0.f, 0.f};

#pragma unroll
    for (int c = 0; c < 8; ++c) {
        const bf16x8 af = *(const bf16x8*)(Pb + q * 4096 + ((c * 512 + w * 64 + g * 16) ^ swzP));
        const char* fb = Vf + (size_t)((c * 8 + w) * 4) * 1024 + lane * 16;
#pragma unroll
        for (int ni = 0; ni < 4; ++ni) {
            const bf16x8 bfr = *(const bf16x8*)(fb + ni * 1024);
            ctx[ni] = __builtin_amdgcn_mfma_f32_16x16x32_bf16(af, bfr, ctx[ni], 0, 0, 0);
        }
    }
    __syncthreads();   // all P reads done; reuse P_lds as f32 partials [8][16][64]

    float* part = (float*)P_lds;
#pragma unroll
    for (int ni = 0; ni < 4; ++ni) {
#pragma unroll
        for (int r = 0; r < 4; ++r) {
            part[(w * 16 + g * 4 + r) * 64 + ni * 16 + q] = ctx[ni][r];
        }
    }
    __syncthreads();

#pragma unroll
    for (int idx = t; idx < 1024; idx += 512) {
        const int qq = idx >> 6, d = idx & 63;
        float s2 = 0.f;
#pragma unroll
        for (int ww = 0; ww < 8; ++ww) s2 += part[ww * 1024 + idx];
        Ctx[(size_t)(b * SEQ + q0 + qq) * DM + h * DEPTH + d] = f2b(s2);
    }
}

extern "C" void kernel_launch(void* const* d_in, const int* in_sizes, int n_in,
                              void* d_out, int out_size, void* d_ws, size_t ws_size,
                              hipStream_t stream) {
    const float* x  = (const float*)d_in[0];
    const float* wq = (const float*)d_in[1];
    const float* bq = (const float*)d_in[2];
    const float* wk = (const float*)d_in[3];
    const float* bk = (const float*)d_in[4];
    const float* wv = (const float*)d_in[5];
    const float* bv = (const float*)d_in[6];
    const float* wo = (const float*)d_in[7];
    const float* bo = (const float*)d_in[8];

    float* out  = (float*)d_out;                          // [2,2048,1024]
    float* attn = out + (size_t)MROWS * DM;               // [2,16,2048,2048] fp32

    ushort* ws  = (ushort*)d_ws;
    ushort* xb  = ws;                        // 4096x1024 bf16
    ushort* wqt = xb + (size_t)MROWS * DM;   // [wqt|wkt|wvt|wot] contiguous, each 1024x1024
    ushort* wot = wqt + (size_t)3 * DM * DM;
    ushort* Qh  = wot + (size_t)DM * DM;     // [Qh|Kh|Vh] contiguous, each 4096x1024 bf16
    ushort* Kh  = Qh + (size_t)MROWS * DM;
    ushort* Vh  = Kh + (size_t)MROWS * DM;
    ushort* cxb = Vh + (size_t)MROWS * DM;
    ushort* Vt3 = cxb + (size_t)MROWS * DM;  // [32 bh][64 kc][4 ni][64 lane][8] bf16, 8MB

    convert_f32_bf16<<<dim3(MROWS * DM / 4 / 256), 256, 0, stream>>>(x, xb, MROWS * DM / 4);
    transpose_convert4<<<dim3(DM / 32, DM / 32, 4), 256, 0, stream>>>(wq, wk, wv, wo, wqt);

    gemm_qkv_mfma<<<dim3(3 * DM / 128, MROWS / 128), 256, 0, stream>>>(xb, wqt, bq, bk, bv, Qh);

    transpose_v<<<dim3(BATCH * NH, SEQ / 64), 256, 0, stream>>>(Vh, Vt3);

    attn_fused_kernel<<<dim3(SEQ / 16, BATCH * NH), 512, 0, stream>>>(Qh, Kh, Vt3, attn, cxb);

    gemm_mfma_f32<<<dim3(DM / 128, MROWS / 128), 256, 0, stream>>>(cxb, wot, bo, out);
}

// Round 18
// 220.017 us; speedup vs baseline: 7.7168x; 1.0089x over previous
//
#include <hip/hip_runtime.h>
#include <hip/hip_bf16.h>

#define SEQ 2048
#define BATCH 2
#define NH 16
#define DM 1024
#define DEPTH 64
#define MROWS (BATCH * SEQ)   // 4096

typedef __attribute__((ext_vector_type(8))) short bf16x8;
typedef __attribute__((ext_vector_type(4))) float f32x4;

__device__ __forceinline__ float b2f(ushort u) {
    union { uint i; float f; } v; v.i = ((uint)u) << 16; return v.f;
}
__device__ __forceinline__ ushort f2b(float f) {
    __hip_bfloat16 h = __float2bfloat16(f);
    return *reinterpret_cast<ushort*>(&h);
}

__device__ __forceinline__ void gload_lds16(const void* g, void* l) {
    __builtin_amdgcn_global_load_lds((const __attribute__((address_space(1))) void*)g,
                                     (__attribute__((address_space(3))) void*)l, 16, 0, 0);
}

// ---------------- fp32 -> bf16 elementwise ----------------
__global__ __launch_bounds__(256) void convert_f32_bf16(const float* __restrict__ in,
                                                        ushort* __restrict__ outp, int n4) {
    int i = blockIdx.x * 256 + threadIdx.x;
    if (i < n4) {
        const float4 v = ((const float4*)in)[i];
        ushort4 o;
        o.x = f2b(v.x); o.y = f2b(v.y); o.z = f2b(v.z); o.w = f2b(v.w);
        ((ushort4*)outp)[i] = o;
    }
}

// ---------------- 4x fused: fp32 W[K][N] -> bf16 Wt[N][K], z selects weight ----------------
__global__ __launch_bounds__(256) void transpose_convert4(const float* __restrict__ w0,
                                                          const float* __restrict__ w1,
                                                          const float* __restrict__ w2,
                                                          const float* __restrict__ w3,
                                                          ushort* __restrict__ WtBase) {
    __shared__ float tile[32][33];
    const int z = blockIdx.z;
    const float* W = (z == 0) ? w0 : (z == 1) ? w1 : (z == 2) ? w2 : w3;
    ushort* Wt = WtBase + (size_t)z * DM * DM;
    const int bx = blockIdx.x * 32;  // n base
    const int by = blockIdx.y * 32;  // k base
    const int tx = threadIdx.x & 31, ty = threadIdx.x >> 5;
#pragma unroll
    for (int i = 0; i < 32; i += 8)
        tile[ty + i][tx] = W[(size_t)(by + ty + i) * DM + bx + tx];
    __syncthreads();
#pragma unroll
    for (int i = 0; i < 32; i += 8)
        Wt[(size_t)(bx + ty + i) * DM + by + tx] = f2b(tile[tx][ty + i]);
}

// ---------------- fused QKV GEMM: [4096,1024] @ [1024,3072] + bias -> bf16 ----------------
// Q bank (bank==0) is pre-scaled by 1/sqrt(DEPTH)=0.125 so attn skips the logit scale.
__global__ __launch_bounds__(256) void gemm_qkv_mfma(const ushort* __restrict__ A,
                                                     const ushort* __restrict__ WtAll,
                                                     const float* __restrict__ bq,
                                                     const float* __restrict__ bk,
                                                     const float* __restrict__ bv,
                                                     ushort* __restrict__ OutBase) {
    __shared__ __align__(16) ushort As[128 * 32];
    __shared__ __align__(16) ushort Bs[128 * 32];

    const int t    = threadIdx.x;
    const int lane = t & 63;
    const int w    = t >> 6;
    const int wr   = w >> 1, wc = w & 1;
    const int row0 = blockIdx.y * 128;
    const int col0 = blockIdx.x * 128;           // 0..2944
    const int bank = col0 >> 10;                 // 0,1,2
    const float* bias = (bank == 0) ? bq : (bank == 1) ? bk : bv;
    const float scale = (bank == 0) ? 0.125f : 1.0f;
    const int ccol0 = col0 & 1023;
    ushort* Cout = OutBase + (size_t)bank * MROWS * DM;

    f32x4 acc[4][4];
#pragma unroll
    for (int mi = 0; mi < 4; ++mi)
#pragma unroll
        for (int ni = 0; ni < 4; ++ni) acc[mi][ni] = (f32x4){0.f, 0.f, 0.f, 0.f};

    const int sr = t >> 2;
    const int sc = (t & 3) * 8;

    for (int k0 = 0; k0 < DM; k0 += 32) {
        gload_lds16(&A[(size_t)(row0 + sr) * DM + k0 + sc],          &As[w * 512]);
        gload_lds16(&A[(size_t)(row0 + 64 + sr) * DM + k0 + sc],     &As[2048 + w * 512]);
        gload_lds16(&WtAll[(size_t)(col0 + sr) * DM + k0 + sc],      &Bs[w * 512]);
        gload_lds16(&WtAll[(size_t)(col0 + 64 + sr) * DM + k0 + sc], &Bs[2048 + w * 512]);
        __syncthreads();

        bf16x8 af[4], bfr[4];
#pragma unroll
        for (int mi = 0; mi < 4; ++mi)
            af[mi] = *(const bf16x8*)&As[(wr * 64 + mi * 16 + (lane & 15)) * 32 + (lane >> 4) * 8];
#pragma unroll
        for (int ni = 0; ni < 4; ++ni)
            bfr[ni] = *(const bf16x8*)&Bs[(wc * 64 + ni * 16 + (lane & 15)) * 32 + (lane >> 4) * 8];
#pragma unroll
        for (int mi = 0; mi < 4; ++mi)
#pragma unroll
            for (int ni = 0; ni < 4; ++ni)
                acc[mi][ni] = __builtin_amdgcn_mfma_f32_16x16x32_bf16(af[mi], bfr[ni], acc[mi][ni], 0, 0, 0);
        __syncthreads();
    }

    float bb[4];
#pragma unroll
    for (int ni = 0; ni < 4; ++ni) bb[ni] = bias[ccol0 + wc * 64 + ni * 16 + (lane & 15)];

#pragma unroll
    for (int mi = 0; mi < 4; ++mi) {
        const int row = row0 + wr * 64 + mi * 16 + (lane >> 4) * 4;
#pragma unroll
        for (int ni = 0; ni < 4; ++ni) {
            const int col = ccol0 + wc * 64 + ni * 16 + (lane & 15);
#pragma unroll
            for (int r = 0; r < 4; ++r)
                Cout[(size_t)(row + r) * DM + col] = f2b((acc[mi][ni][r] + bb[ni]) * scale);
        }
    }
}

// ---------------- bf16 MFMA GEMM: C = A @ Wt^T + bias, fp32 out ----------------
__global__ __launch_bounds__(256) void gemm_mfma_f32(const ushort* __restrict__ A,
                                                     const ushort* __restrict__ Wt,
                                                     const float* __restrict__ bias,
                                                     float* __restrict__ Cout) {
    __shared__ __align__(16) ushort As[128 * 32];
    __shared__ __align__(16) ushort Bs[128 * 32];

    const int t    = threadIdx.x;
    const int lane = t & 63;
    const int w    = t >> 6;
    const int wr   = w >> 1, wc = w & 1;
    const int row0 = blockIdx.y * 128;
    const int col0 = blockIdx.x * 128;

    f32x4 acc[4][4];
#pragma unroll
    for (int mi = 0; mi < 4; ++mi)
#pragma unroll
        for (int ni = 0; ni < 4; ++ni) acc[mi][ni] = (f32x4){0.f, 0.f, 0.f, 0.f};

    const int sr = t >> 2;
    const int sc = (t & 3) * 8;

    for (int k0 = 0; k0 < DM; k0 += 32) {
        gload_lds16(&A[(size_t)(row0 + sr) * DM + k0 + sc],       &As[w * 512]);
        gload_lds16(&A[(size_t)(row0 + 64 + sr) * DM + k0 + sc],  &As[2048 + w * 512]);
        gload_lds16(&Wt[(size_t)(col0 + sr) * DM + k0 + sc],      &Bs[w * 512]);
        gload_lds16(&Wt[(size_t)(col0 + 64 + sr) * DM + k0 + sc], &Bs[2048 + w * 512]);
        __syncthreads();

        bf16x8 af[4], bfr[4];
#pragma unroll
        for (int mi = 0; mi < 4; ++mi)
            af[mi] = *(const bf16x8*)&As[(wr * 64 + mi * 16 + (lane & 15)) * 32 + (lane >> 4) * 8];
#pragma unroll
        for (int ni = 0; ni < 4; ++ni)
            bfr[ni] = *(const bf16x8*)&Bs[(wc * 64 + ni * 16 + (lane & 15)) * 32 + (lane >> 4) * 8];
#pragma unroll
        for (int mi = 0; mi < 4; ++mi)
#pragma unroll
            for (int ni = 0; ni < 4; ++ni)
                acc[mi][ni] = __builtin_amdgcn_mfma_f32_16x16x32_bf16(af[mi], bfr[ni], acc[mi][ni], 0, 0, 0);
        __syncthreads();
    }

    float bb[4];
#pragma unroll
    for (int ni = 0; ni < 4; ++ni) bb[ni] = bias[col0 + wc * 64 + ni * 16 + (lane & 15)];

#pragma unroll
    for (int mi = 0; mi < 4; ++mi) {
        const int row = row0 + wr * 64 + mi * 16 + (lane >> 4) * 4;
#pragma unroll
        for (int ni = 0; ni < 4; ++ni) {
            const int col = col0 + wc * 64 + ni * 16 + (lane & 15);
#pragma unroll
            for (int r = 0; r < 4; ++r)
                Cout[(size_t)(row + r) * DM + col] = acc[mi][ni][r] + bb[ni];
        }
    }
}

// ---------------- V transpose -> fragment-linear Vt3 (verified R16) ----------------
// Vt3[bh][kc=key/32][ni=d/16][lane][8] bf16: exact MFMA B-fragment order.
__global__ __launch_bounds__(256) void transpose_v(const ushort* __restrict__ Vh,
                                                   ushort* __restrict__ Vt3) {
    __shared__ ushort tile[64][80];
    const int t  = threadIdx.x;
    const int bh = blockIdx.x;
    const int cc = blockIdx.y;        // 64-key group
    const int k0 = cc * 64;
    const int b  = bh >> 4;
    const int h  = bh & 15;
    const size_t panel = (size_t)b * SEQ * DM + (size_t)h * DEPTH;

    {
        const int k = t >> 2, dc = (t & 3) * 16;
        const ushort* src = Vh + panel + (size_t)(k0 + k) * DM + dc;
        *(bf16x8*)&tile[k][dc]     = *(const bf16x8*)src;
        *(bf16x8*)&tile[k][dc + 8] = *(const bf16x8*)(src + 8);
    }
    __syncthreads();
    {
        const int l  = t & 63;
        const int ni = t >> 6;        // 0..3
        const int kr = (l >> 4) * 8;
        const int dl = ni * 16 + (l & 15);
#pragma unroll
        for (int kh = 0; kh < 2; ++kh) {
            bf16x8 o;
#pragma unroll
            for (int j = 0; j < 8; ++j) o[j] = tile[kh * 32 + kr + j][dl];
            char* dst = (char*)Vt3 +
                        (((size_t)bh * 64 + cc * 2 + kh) * 4 + ni) * 1024 + l * 16;
            *(bf16x8*)dst = o;
        }
    }
}

// ---------------- K transpose -> fragment-linear Kf ----------------
// Kf[bh][kt=key/16][ks=d/32][lane][8] bf16: exact MFMA A-fragment order (verified map:
// lane l holds K[kt*16 + (l&15)][ks*32 + (l>>4)*8 + j]). QK loads become 1KB contiguous.
__global__ __launch_bounds__(256) void transpose_k(const ushort* __restrict__ Kh,
                                                   ushort* __restrict__ Kf) {
    __shared__ ushort tile[64][80];
    const int t  = threadIdx.x;
    const int bh = blockIdx.x;
    const int cc = blockIdx.y;        // 64-key group
    const int k0 = cc * 64;
    const int b  = bh >> 4;
    const int h  = bh & 15;
    const size_t panel = (size_t)b * SEQ * DM + (size_t)h * DEPTH;

    {
        const int k = t >> 2, dc = (t & 3) * 16;
        const ushort* src = Kh + panel + (size_t)(k0 + k) * DM + dc;
        *(bf16x8*)&tile[k][dc]     = *(const bf16x8*)src;
        *(bf16x8*)&tile[k][dc + 8] = *(const bf16x8*)(src + 8);
    }
    __syncthreads();
    {
        const int l   = t & 63;
        const int sub = t >> 6;       // kt_local 0..3
        const int row = sub * 16 + (l & 15);
        const int db  = (l >> 4) * 8;
#pragma unroll
        for (int ks = 0; ks < 2; ++ks) {
            bf16x8 o;
#pragma unroll
            for (int j = 0; j < 8; ++j) o[j] = tile[row][ks * 32 + db + j];
            char* dst = (char*)Kf +
                        ((((size_t)bh * 128 + cc * 4 + sub) * 2) + ks) * 1024 + l * 16;
            *(bf16x8*)dst = o;
        }
    }
}

// ---------------- fused attention v11: fragment-linear K AND V (zero-staging QK+PV) --------
// 512 threads (8 waves), one (b,h) x 16 q-rows. Wave w owns keys [w*256, w*256+256)
// (R11-verified ownership/pack/PV offsets). QK: 16 barrier-free iters of
// {2 x 1KB contiguous Kf loads + 2 MFMA}. PV: same pattern on Vt3 (verified R16).
// Only ~6 block barriers total (softmax stats + pack + reduce).
__global__ __launch_bounds__(512, 2) void attn_fused_kernel(const ushort* __restrict__ Qh,
                                                            const ushort* __restrict__ Kfrag,
                                                            const ushort* __restrict__ Vt3,
                                                            float* __restrict__ attn_out,
                                                            ushort* __restrict__ Ctx) {
    __shared__ __align__(16) ushort P_lds[16 * 2048];   // 64 KB: P tile -> partials
    __shared__ float red[256];                          // softmax stats

    const int t    = threadIdx.x;
    const int lane = t & 63;
    const int w    = t >> 6;          // 0..7
    const int qt   = blockIdx.x;      // fast axis -> panel-major dispatch
    const int bh   = blockIdx.y;
    const int b    = bh >> 4;
    const int h    = bh & 15;
    const int q0   = qt * 16;
    const int q    = lane & 15;
    const int g    = lane >> 4;       // 0..3
    const int swzP = (q & 7) << 4;

    const size_t panel = (size_t)b * SEQ * DM + (size_t)h * DEPTH;
    char* Pb = (char*)P_lds;

    const ushort* Qrow = Qh + panel + (size_t)(q0 + q) * DM + g * 8;
    const bf16x8 qf0 = *(const bf16x8*)Qrow;
    const bf16x8 qf1 = *(const bf16x8*)(Qrow + 32);

    // ---- QK^T: wave w -> kt tiles w*16 .. w*16+15, direct fragment-linear loads
    const char* Kf = (const char*)Kfrag + (size_t)bh * 262144;   // 128 kt x 2 ks x 1KB
    f32x4 acc[16];
#pragma unroll
    for (int i = 0; i < 16; ++i) acc[i] = (f32x4){0.f, 0.f, 0.f, 0.f};

#pragma unroll
    for (int i = 0; i < 16; ++i) {
        const char* fb = Kf + (size_t)((w * 16 + i) * 2) * 1024 + lane * 16;
        const bf16x8 kf0 = *(const bf16x8*)fb;
        const bf16x8 kf1 = *(const bf16x8*)(fb + 1024);
        acc[i] = __builtin_amdgcn_mfma_f32_16x16x32_bf16(kf0, qf0, acc[i], 0, 0, 0);  // swapped
        acc[i] = __builtin_amdgcn_mfma_f32_16x16x32_bf16(kf1, qf1, acc[i], 0, 0, 0);
    }

    // ---- softmax stats: lane-local -> lanes {q,q+16,q+32,q+48} -> waves
    float mm = acc[0][0];
#pragma unroll
    for (int i = 0; i < 16; ++i) {
#pragma unroll
        for (int r = 0; r < 4; ++r) mm = fmaxf(mm, acc[i][r]);
    }
    mm = fmaxf(mm, __shfl_xor(mm, 16));
    mm = fmaxf(mm, __shfl_xor(mm, 32));
    if (lane < 16) red[w * 16 + lane] = mm;
    __syncthreads();

    float mx = red[q];
#pragma unroll
    for (int ww = 1; ww < 8; ++ww) mx = fmaxf(mx, red[ww * 16 + q]);

    float ssum = 0.f;
#pragma unroll
    for (int i = 0; i < 16; ++i) {
#pragma unroll
        for (int r = 0; r < 4; ++r) {
            const float p = __expf(acc[i][r] - mx);
            acc[i][r] = p;
            ssum += p;
        }
    }
    ssum += __shfl_xor(ssum, 16);
    ssum += __shfl_xor(ssum, 32);
    if (lane < 16) red[128 + w * 16 + lane] = ssum;
    __syncthreads();

    float tot = red[128 + q];
#pragma unroll
    for (int ww = 1; ww < 8; ++ww) tot += red[128 + ww * 16 + q];
    const float rinv = 1.f / tot;

    // ---- pack normalized P (bf16, swizzled): key w*256 + i*16 + g*4 + r (R11-verified)
#pragma unroll
    for (int i = 0; i < 16; ++i) {
        const float p0 = acc[i][0] * rinv;
        const float p1 = acc[i][1] * rinv;
        const float p2 = acc[i][2] * rinv;
        const float p3 = acc[i][3] * rinv;
        uint2 uu;
        uu.x = (uint)f2b(p0) | ((uint)f2b(p1) << 16);
        uu.y = (uint)f2b(p2) | ((uint)f2b(p3) << 16);
        *(uint2*)(Pb + q * 4096 + ((w * 512 + i * 32 + g * 8) ^ swzP)) = uu;
    }
    __syncthreads();

    // ---- attn store: wave w writes rows 0..15, cols [w*256,+256); 1KB/inst, NT
    float* attn_base = attn_out + ((size_t)bh * SEQ + q0) * SEQ;
#pragma unroll
    for (int it = 0; it < 16; ++it) {
        const int bofs = (w * 512 + lane * 8) ^ ((it & 7) << 4);
        const ushort4 p4 = *(const ushort4*)(Pb + it * 4096 + bofs);
        f32x4 o;
        o[0] = b2f(p4.x); o[1] = b2f(p4.y); o[2] = b2f(p4.z); o[3] = b2f(p4.w);
        __builtin_nontemporal_store(o, (f32x4*)&attn_base[(size_t)it * SEQ + w * 256 + lane * 4]);
    }

    // ---- PV: wave w over keys {w*256 + s8*32 .. +32}; V fragment-linear (verified R16)
    const char* Vf = (const char*)Vt3 + (size_t)bh * 262144;   // 64 kc x 4 ni x 1KB
    f32x4 ctx[4];
#pragma unroll
    for (int ni = 0; ni < 4; ++ni) ctx[ni] = (f32x4){0.f, 0.f, 0.f, 0.f};

#pragma unroll
    for (int s8 = 0; s8 < 8; ++s8) {
        const bf16x8 af = *(const bf16x8*)(Pb + q * 4096 + ((w * 512 + s8 * 64 + g * 16) ^ swzP));
        const char* fb = Vf + (size_t)((w * 8 + s8) * 4) * 1024 + lane * 16;
#pragma unroll
        for (int ni = 0; ni < 4; ++ni) {
            const bf16x8 bfr = *(const bf16x8*)(fb + ni * 1024);
            ctx[ni] = __builtin_amdgcn_mfma_f32_16x16x32_bf16(af, bfr, ctx[ni], 0, 0, 0);
        }
    }
    __syncthreads();   // all P reads done; reuse P_lds as f32 partials [8][16][64]

    float* part = (float*)P_lds;
#pragma unroll
    for (int ni = 0; ni < 4; ++ni) {
#pragma unroll
        for (int r = 0; r < 4; ++r) {
            part[(w * 16 + g * 4 + r) * 64 + ni * 16 + q] = ctx[ni][r];
        }
    }
    __syncthreads();

#pragma unroll
    for (int idx = t; idx < 1024; idx += 512) {
        const int qq = idx >> 6, d = idx & 63;
        float s2 = 0.f;
#pragma unroll
        for (int ww = 0; ww < 8; ++ww) s2 += part[ww * 1024 + idx];
        Ctx[(size_t)(b * SEQ + q0 + qq) * DM + h * DEPTH + d] = f2b(s2);
    }
}

extern "C" void kernel_launch(void* const* d_in, const int* in_sizes, int n_in,
                              void* d_out, int out_size, void* d_ws, size_t ws_size,
                              hipStream_t stream) {
    const float* x  = (const float*)d_in[0];
    const float* wq = (const float*)d_in[1];
    const float* bq = (const float*)d_in[2];
    const float* wk = (const float*)d_in[3];
    const float* bk = (const float*)d_in[4];
    const float* wv = (const float*)d_in[5];
    const float* bv = (const float*)d_in[6];
    const float* wo = (const float*)d_in[7];
    const float* bo = (const float*)d_in[8];

    float* out  = (float*)d_out;                          // [2,2048,1024]
    float* attn = out + (size_t)MROWS * DM;               // [2,16,2048,2048] fp32

    ushort* ws  = (ushort*)d_ws;
    ushort* xb  = ws;                        // 4096x1024 bf16
    ushort* wqt = xb + (size_t)MROWS * DM;   // [wqt|wkt|wvt|wot] contiguous, each 1024x1024
    ushort* wot = wqt + (size_t)3 * DM * DM;
    ushort* Qh  = wot + (size_t)DM * DM;     // [Qh|Kh|Vh] contiguous, each 4096x1024 bf16
    ushort* Kh  = Qh + (size_t)MROWS * DM;
    ushort* Vh  = Kh + (size_t)MROWS * DM;
    ushort* cxb = Vh + (size_t)MROWS * DM;
    ushort* Vt3 = cxb + (size_t)MROWS * DM;  // [32 bh][64 kc][4 ni][64 lane][8] bf16, 8MB
    ushort* Kf  = Vt3 + (size_t)BATCH * NH * DEPTH * SEQ;  // [32 bh][128 kt][2 ks][64][8], 8MB

    convert_f32_bf16<<<dim3(MROWS * DM / 4 / 256), 256, 0, stream>>>(x, xb, MROWS * DM / 4);
    transpose_convert4<<<dim3(DM / 32, DM / 32, 4), 256, 0, stream>>>(wq, wk, wv, wo, wqt);

    gemm_qkv_mfma<<<dim3(3 * DM / 128, MROWS / 128), 256, 0, stream>>>(xb, wqt, bq, bk, bv, Qh);

    transpose_v<<<dim3(BATCH * NH, SEQ / 64), 256, 0, stream>>>(Vh, Vt3);
    transpose_k<<<dim3(BATCH * NH, SEQ / 64), 256, 0, stream>>>(Kh, Kf);

    attn_fused_kernel<<<dim3(SEQ / 16, BATCH * NH), 512, 0, stream>>>(Qh, Kf, Vt3, attn, cxb);

    gemm_mfma_f32<<<dim3(DM / 128, MROWS / 128), 256, 0, stream>>>(cxb, wot, bo, out);
}